// Round 12
// baseline (1457.390 us; speedup 1.0000x reference)
//
#include <hip/hip_runtime.h>
#include <math.h>

// Problem constants (from reference)
#define DIMS   1024
#define NHEAD  16
#define HD     64
#define WIN    512
#define CTX    4096
#define NBATCH 4
#define NROWS  (NBATCH*CTX)        // 16384 total sequence rows
#define NUNITS (NROWS*NHEAD)       // 262144 (row,head) units
#define LNEPS  1e-5f
#define FIXSCALE 16777216.0        // 2^24 fixed-point for deterministic diff

typedef __attribute__((ext_vector_type(8))) short bf16x8;   // 8 bf16 (4 VGPR)
typedef __attribute__((ext_vector_type(4))) float f32x4;    // MFMA C/D

__device__ __forceinline__ float4 ld4(const float* p) { return *reinterpret_cast<const float4*>(p); }
__device__ __forceinline__ void st4(float* p, float4 v) { *reinterpret_cast<float4*>(p) = v; }

__device__ __forceinline__ float wave_sum64(float v) {
#pragma unroll
    for (int off = 32; off; off >>= 1) v += __shfl_xor(v, off, 64);
    return v;
}
__device__ __forceinline__ float grp16_sum(float v) {
    v += __shfl_xor(v, 1, 64);
    v += __shfl_xor(v, 2, 64);
    v += __shfl_xor(v, 4, 64);
    v += __shfl_xor(v, 8, 64);
    return v;
}

// round-to-nearest-even bf16 of x, packed split: (hi<<16)|lo with hi+lo ~= x (err ~2^-17)
__device__ __forceinline__ unsigned bf16_rn_bits(float x) {
    unsigned u = __float_as_uint(x);
    return (u + 0x7fffu + ((u >> 16) & 1u)) >> 16;
}
__device__ __forceinline__ unsigned pack_hl(float x) {
    unsigned h = bf16_rn_bits(x);
    float hf = __uint_as_float(h << 16);
    unsigned l = bf16_rn_bits(x - hf);
    return (h << 16) | (l & 0xffffu);
}

// v_cvt_pk_bf16_f32: D[15:0]=bf16(a), D[31:16]=bf16(b)  (T12 recipe)
__device__ __forceinline__ unsigned cvtpk_bf16(float a, float b) {
    unsigned r;
    asm volatile("v_cvt_pk_bf16_f32 %0, %1, %2" : "=v"(r) : "v"(a), "v"(b));
    return r;
}
__device__ __forceinline__ void split_pair(float a, float b, unsigned& hw, unsigned& lw) {
    hw = cvtpk_bf16(a, b);
    float ha = __uint_as_float(hw << 16);
    float hb = __uint_as_float(hw & 0xffff0000u);
    lw = cvtpk_bf16(a - ha, b - hb);
}

// XOR-swizzled byte offset into a [rows][64] short LDS plane (stride 128 B)
__device__ __forceinline__ int swzo(int row, int kbyte) {
    return ((row << 7) + kbyte) ^ ((row & 7) << 4);
}

// -------- LayerNorm over D=1024, SPLIT hi/lo bf16 plane output ---------------
__global__ __launch_bounds__(256)
void ln1024_split_kernel(const float* __restrict__ x, const float* __restrict__ w,
                         unsigned short* __restrict__ hp, unsigned short* __restrict__ lp) {
    int r = blockIdx.x;
    int tid = threadIdx.x;
    const float* xr = x + (size_t)r * DIMS;
    float4 v = ld4(xr + (tid << 2));
    __shared__ float red[8];
    float s = wave_sum64(v.x + v.y + v.z + v.w);
    int wv = tid >> 6, lane = tid & 63;
    if (lane == 0) red[wv] = s;
    __syncthreads();
    float mean = (red[0] + red[1] + red[2] + red[3]) * (1.0f / DIMS);
    float dx = v.x - mean, dy = v.y - mean, dz = v.z - mean, dw = v.w - mean;
    float ss = wave_sum64(dx*dx + dy*dy + dz*dz + dw*dw);
    if (lane == 0) red[4 + wv] = ss;
    __syncthreads();
    float inv = rsqrtf((red[4] + red[5] + red[6] + red[7]) * (1.0f / DIMS) + LNEPS);
    float4 wv4 = ld4(w + (tid << 2));
    unsigned h0, l0, h1, l1;
    split_pair(dx * inv * wv4.x, dy * inv * wv4.y, h0, l0);
    split_pair(dz * inv * wv4.z, dw * inv * wv4.w, h1, l1);
    size_t base = (size_t)r * DIMS + (tid << 2);
    *reinterpret_cast<uint2*>(hp + base) = make_uint2(h0, h1);
    *reinterpret_cast<uint2*>(lp + base) = make_uint2(l0, l1);
}

// -------- one-time weight split: W f32 [1024][1024] -> hi/lo bf16 planes -----
__global__ __launch_bounds__(256)
void presplit_w_kernel(const float* __restrict__ W, unsigned short* __restrict__ hp,
                       unsigned short* __restrict__ lp) {
    size_t gid = (size_t)blockIdx.x * 256 + threadIdx.x;
    size_t base = gid << 2;
    float4 v = ld4(W + base);
    unsigned h0, l0, h1, l1;
    split_pair(v.x, v.y, h0, l0);
    split_pair(v.z, v.w, h1, l1);
    *reinterpret_cast<uint2*>(hp + base) = make_uint2(h0, h1);
    *reinterpret_cast<uint2*>(lp + base) = make_uint2(l0, l1);
}

// -------- bf16 hi/lo 3-term MFMA GEMM; A always pre-split; W per PREW --------
// DO_HLN: fused per-head LN epilogue (wave's 64-col tile = one head).
template<int DO_HLN, int PREW>
__global__ __launch_bounds__(256, 2)
void gemm_hl_kernel(const unsigned short* __restrict__ Ahp, const unsigned short* __restrict__ Alp,
                    const float* __restrict__ Wf,
                    const unsigned short* __restrict__ Whp, const unsigned short* __restrict__ Wlp,
                    const float* __restrict__ bias, float* __restrict__ Cm,
                    float alpha, int has_bias, const float* __restrict__ lnw) {
    __shared__ short Ah[128 * 64], Al[128 * 64], Wh[128 * 64], Wl[128 * 64]; // 64 KiB
    int tid = threadIdx.x;
    int wid = tid >> 6, lane = tid & 63;
    int wm = (wid >> 1) << 6, wn = (wid & 1) << 6;
    int g4 = lane >> 4, l16 = lane & 15;
    int m0 = blockIdx.x << 7, n0 = blockIdx.y << 7;

    f32x4 acc[4][4] = {};

    int orow[4], okb[4];
#pragma unroll
    for (int j = 0; j < 4; ++j) {
        int oc = tid + (j << 8);
        orow[j] = oc >> 3;
        okb[j] = (oc & 7) << 4;
    }

    for (int k0 = 0; k0 < 1024; k0 += 64) {
        uint4 ah4[4], al4[4], wh4[4], wl4[4];
        float4 wf0[4], wf1[4];
#pragma unroll
        for (int j = 0; j < 4; ++j) {
            size_t abase = (size_t)(m0 + orow[j]) * 1024 + k0 + (okb[j] >> 1);
            ah4[j] = *reinterpret_cast<const uint4*>(Ahp + abase);
            al4[j] = *reinterpret_cast<const uint4*>(Alp + abase);
            size_t wbase = (size_t)(n0 + orow[j]) * 1024 + k0 + (okb[j] >> 1);
            if (PREW) {
                wh4[j] = *reinterpret_cast<const uint4*>(Whp + wbase);
                wl4[j] = *reinterpret_cast<const uint4*>(Wlp + wbase);
            } else {
                wf0[j] = ld4(Wf + wbase);
                wf1[j] = ld4(Wf + wbase + 4);
            }
        }
        __syncthreads();   // prior iteration's fragment reads complete
#pragma unroll
        for (int j = 0; j < 4; ++j) {
            int off = swzo(orow[j], okb[j]);
            *reinterpret_cast<uint4*>(reinterpret_cast<char*>(Ah) + off) = ah4[j];
            *reinterpret_cast<uint4*>(reinterpret_cast<char*>(Al) + off) = al4[j];
            if (!PREW) {
                split_pair(wf0[j].x, wf0[j].y, wh4[j].x, wl4[j].x);
                split_pair(wf0[j].z, wf0[j].w, wh4[j].y, wl4[j].y);
                split_pair(wf1[j].x, wf1[j].y, wh4[j].z, wl4[j].z);
                split_pair(wf1[j].z, wf1[j].w, wh4[j].w, wl4[j].w);
            }
            *reinterpret_cast<uint4*>(reinterpret_cast<char*>(Wh) + off) = wh4[j];
            *reinterpret_cast<uint4*>(reinterpret_cast<char*>(Wl) + off) = wl4[j];
        }
        __syncthreads();

#pragma unroll
        for (int kk = 0; kk < 2; ++kk) {
            bf16x8 afh[4], afl[4], wfh[4], wfl[4];
#pragma unroll
            for (int mt = 0; mt < 4; ++mt) {
                int row = wm + (mt << 4) + l16;
                int off = ((row << 7) + (kk << 6) + (g4 << 4)) ^ ((row & 7) << 4);
                afh[mt] = *reinterpret_cast<const bf16x8*>(reinterpret_cast<const char*>(Ah) + off);
                afl[mt] = *reinterpret_cast<const bf16x8*>(reinterpret_cast<const char*>(Al) + off);
            }
#pragma unroll
            for (int nt = 0; nt < 4; ++nt) {
                int row = wn + (nt << 4) + l16;
                int off = ((row << 7) + (kk << 6) + (g4 << 4)) ^ ((row & 7) << 4);
                wfh[nt] = *reinterpret_cast<const bf16x8*>(reinterpret_cast<const char*>(Wh) + off);
                wfl[nt] = *reinterpret_cast<const bf16x8*>(reinterpret_cast<const char*>(Wl) + off);
            }
#pragma unroll
            for (int mt = 0; mt < 4; ++mt)
#pragma unroll
                for (int nt = 0; nt < 4; ++nt) {
                    acc[mt][nt] = __builtin_amdgcn_mfma_f32_16x16x32_bf16(afh[mt], wfh[nt], acc[mt][nt], 0, 0, 0);
                    acc[mt][nt] = __builtin_amdgcn_mfma_f32_16x16x32_bf16(afl[mt], wfh[nt], acc[mt][nt], 0, 0, 0);
                    acc[mt][nt] = __builtin_amdgcn_mfma_f32_16x16x32_bf16(afh[mt], wfl[nt], acc[mt][nt], 0, 0, 0);
                }
        }
    }

    if (DO_HLN) {
        float bb[4];
#pragma unroll
        for (int nt = 0; nt < 4; ++nt)
            bb[nt] = has_bias ? bias[n0 + wn + (nt << 4) + l16] : 0.0f;
        float lw4[4];
#pragma unroll
        for (int nt = 0; nt < 4; ++nt) lw4[nt] = lnw[(nt << 4) + l16];
#pragma unroll
        for (int mt = 0; mt < 4; ++mt)
#pragma unroll
            for (int r = 0; r < 4; ++r) {
                float v[4];
                float s1 = 0.0f;
#pragma unroll
                for (int nt = 0; nt < 4; ++nt) {
                    v[nt] = alpha * (acc[mt][nt][r] + bb[nt]);
                    s1 += v[nt];
                }
                s1 = grp16_sum(s1);
                float mean = s1 * (1.0f / 64.0f);
                float s2 = 0.0f;
#pragma unroll
                for (int nt = 0; nt < 4; ++nt) { v[nt] -= mean; s2 += v[nt] * v[nt]; }
                s2 = grp16_sum(s2);
                float inv = rsqrtf(s2 * (1.0f / 64.0f) + LNEPS);
                int row = m0 + wm + (mt << 4) + (g4 << 2) + r;
#pragma unroll
                for (int nt = 0; nt < 4; ++nt)
                    Cm[(size_t)row * DIMS + n0 + wn + (nt << 4) + l16] = v[nt] * inv * lw4[nt];
            }
    } else {
#pragma unroll
        for (int mt = 0; mt < 4; ++mt)
#pragma unroll
            for (int nt = 0; nt < 4; ++nt) {
                int col = n0 + wn + (nt << 4) + l16;
                float bb = has_bias ? bias[col] : 0.0f;
#pragma unroll
                for (int r = 0; r < 4; ++r) {
                    int row = m0 + wm + (mt << 4) + (g4 << 2) + r;
                    Cm[(size_t)row * DIMS + col] = alpha * (acc[mt][nt][r] + bb);
                }
            }
    }
}

// -------- kp projection + LN + hi/lo split -> packed K plane (unchanged) -----
__global__ __launch_bounds__(256)
void proj64_khl_kernel(const float* __restrict__ inp, const float* __restrict__ W,
                       const float* __restrict__ Wb, const float* __restrict__ lnw,
                       unsigned* __restrict__ plane) {
    int u0 = blockIdx.x << 6;
    __shared__ float As[64][68];
    __shared__ float Bs[64][68];
    int tid = threadIdx.x;
    for (int e = tid; e < 4096; e += 256) Bs[e & 63][e >> 6] = W[e];
    for (int e = tid; e < 1024; e += 256) {
        int row = e >> 4;
        int col = (e & 15) << 2;
        float4 v = ld4(inp + ((size_t)(u0 + row) << 6) + col);
        As[col + 0][row] = v.x; As[col + 1][row] = v.y;
        As[col + 2][row] = v.z; As[col + 3][row] = v.w;
    }
    __syncthreads();
    int tm = tid >> 4, tn = tid & 15;
    float acc[4][4] = {};
#pragma unroll
    for (int k = 0; k < 64; ++k) {
        float4 av = ld4(&As[k][tm << 2]);
        float4 bv = ld4(&Bs[k][tn << 2]);
        float aa[4] = {av.x, av.y, av.z, av.w};
        float bb[4] = {bv.x, bv.y, bv.z, bv.w};
#pragma unroll
        for (int mm = 0; mm < 4; ++mm)
#pragma unroll
            for (int nn = 0; nn < 4; ++nn)
                acc[mm][nn] = fmaf(aa[mm], bb[nn], acc[mm][nn]);
    }
    float bb4[4] = {Wb[(tn << 2) + 0], Wb[(tn << 2) + 1], Wb[(tn << 2) + 2], Wb[(tn << 2) + 3]};
    float lw4[4] = {lnw[(tn << 2) + 0], lnw[(tn << 2) + 1], lnw[(tn << 2) + 2], lnw[(tn << 2) + 3]};
#pragma unroll
    for (int mm = 0; mm < 4; ++mm) {
        float o0 = acc[mm][0] + bb4[0], o1 = acc[mm][1] + bb4[1];
        float o2 = acc[mm][2] + bb4[2], o3 = acc[mm][3] + bb4[3];
        float mean = grp16_sum(o0 + o1 + o2 + o3) * (1.0f / 64.0f);
        float d0 = o0 - mean, d1 = o1 - mean, d2 = o2 - mean, d3 = o3 - mean;
        float var = grp16_sum(d0*d0 + d1*d1 + d2*d2 + d3*d3) * (1.0f / 64.0f);
        float inv = rsqrtf(var + LNEPS);
        o0 = d0 * inv * lw4[0]; o1 = d1 * inv * lw4[1];
        o2 = d2 * inv * lw4[2]; o3 = d3 * inv * lw4[3];
        int u_p = u0 + (tm << 2) + mm;
        int r = u_p >> 4, h = u_p & 15;
        int s = r & 511;
        int ua = ((r >> 9) << 4) + h;
        size_t punit = (size_t)ua * 512 + s;
        uint4 pk;
        pk.x = pack_hl(o0); pk.y = pack_hl(o1); pk.z = pack_hl(o2); pk.w = pack_hl(o3);
        *reinterpret_cast<uint4*>(plane + (punit << 6) + (tn << 2)) = pk;
    }
}

// -------- vp projection + hi/lo split -> packed transposed V plane (unchanged)
__global__ __launch_bounds__(256)
void proj64_vthl_kernel(const float* __restrict__ inp, const float* __restrict__ W,
                        const float* __restrict__ Wb, unsigned* __restrict__ plane) {
    int u0 = blockIdx.x << 6;
    __shared__ float As[64][68];
    __shared__ float Bs[64][68];
    int tid = threadIdx.x;
    for (int e = tid; e < 4096; e += 256) Bs[e & 63][e >> 6] = W[e];
    for (int e = tid; e < 1024; e += 256) {
        int row = e >> 4;
        int col = (e & 15) << 2;
        float4 v = ld4(inp + ((size_t)(u0 + row) << 6) + col);
        As[col + 0][row] = v.x; As[col + 1][row] = v.y;
        As[col + 2][row] = v.z; As[col + 3][row] = v.w;
    }
    __syncthreads();
    int tm = tid >> 4, tn = tid & 15;
    float acc[4][4] = {};
#pragma unroll
    for (int k = 0; k < 64; ++k) {
        float4 av = ld4(&As[k][tm << 2]);
        float4 bv = ld4(&Bs[k][tn << 2]);
        float aa[4] = {av.x, av.y, av.z, av.w};
        float bb[4] = {bv.x, bv.y, bv.z, bv.w};
#pragma unroll
        for (int mm = 0; mm < 4; ++mm)
#pragma unroll
            for (int nn = 0; nn < 4; ++nn)
                acc[mm][nn] = fmaf(aa[mm], bb[nn], acc[mm][nn]);
    }
    float bb4[4] = {Wb[(tn << 2) + 0], Wb[(tn << 2) + 1], Wb[(tn << 2) + 2], Wb[(tn << 2) + 3]};
#pragma unroll
    for (int mm = 0; mm < 4; ++mm) {
        int u_p = u0 + (tm << 2) + mm;
        int r = u_p >> 4, h = u_p & 15;
        int s = r & 511;
        int ua = ((r >> 9) << 4) + h;
        size_t base = ((size_t)(ua * 8 + (s >> 6)) << 12) + (s & 63);
#pragma unroll
        for (int nn = 0; nn < 4; ++nn) {
            int d = (tn << 2) + nn;
            plane[base + ((size_t)d << 6)] = pack_hl(acc[mm][nn] + bb4[nn]);
        }
    }
}

// -------- fused MFMA attention: TWO q-tiles per block (EXACT R9 version) -----
template<int DIFF, int USE_CONV>
__global__ __launch_bounds__(256)
void attn_mfma_kernel(const float* __restrict__ qacc, const unsigned* __restrict__ khl,
                      const unsigned* __restrict__ vthl, float* __restrict__ o_io,
                      const float* __restrict__ lqw, const float* __restrict__ lqb,
                      const float* __restrict__ lnw,
                      unsigned long long* __restrict__ diff_acc,
                      const int* __restrict__ conv) {
    __shared__ short kh[64][72], kl[64][72], vh[64][72], vl[64][72];   // 36864 B
    __shared__ float dred[4];

    int blk = blockIdx.x;
    int u = blk & 511;
    int pr = blk >> 9;             // 0..3
    int tHi = 7 - (pr << 1);       // 7,5,3,1 (heavy pairs launch first)
    int tLo = tHi - 1;             // 6,4,2,0
    int h = u & 15;
    int w = (u >> 4) & 7;
    int b = u >> 7;
    if (USE_CONV && conv[w]) return;
    int rowbase = b * CTX + w * WIN;
    int col0 = h * HD;
    int tid = threadIdx.x;
    int wv = tid >> 6;
    int lane = tid & 63;
    int g4 = lane >> 4;
    int qcol = lane & 15;
    int q_loc = (wv << 4) + qcol;
    int selhi = g4 >> 1;

    const unsigned* kbase = khl + (((size_t)u * 512) << 6);
    const unsigned* vbase = vthl + (((size_t)u * 8) << 12);

    // ---- prefetch chunk 0 K,V (hides under phase A) ----
    uint4 kpre[4], vpre[4];
#pragma unroll
    for (int rr = 0; rr < 4; ++rr) {
        int row = (wv << 4) + (rr << 2) + g4;
        kpre[rr] = *reinterpret_cast<const uint4*>(kbase + ((size_t)row << 6) + (qcol << 2));
        vpre[rr] = *reinterpret_cast<const uint4*>(vbase + ((size_t)row << 6) + (qcol << 2));
    }

    // ---- phase A: stage lqw once; per tile qp^T = mfma(lqw, qacc^T) + LN ----
#pragma unroll
    for (int rr = 0; rr < 4; ++rr) {
        int row = (wv << 4) + (rr << 2) + g4;
        float4 v = ld4(lqw + (row << 6) + (qcol << 2));
        unsigned h0, l0, h1, l1;
        split_pair(v.x, v.y, h0, l0);
        split_pair(v.z, v.w, h1, l1);
        *reinterpret_cast<uint2*>(&kh[row][qcol << 2]) = make_uint2(h0, h1);
        *reinterpret_cast<uint2*>(&kl[row][qcol << 2]) = make_uint2(l0, l1);
    }
    __syncthreads();   // lqw staged

    bf16x8 qfh[2][2], qfl[2][2];   // [tile][kb]
#pragma unroll
    for (int ti = 0; ti < 2; ++ti) {
        int T = ti ? tLo : tHi;
        bf16x8 bqh[2], bql[2];
        {
            const float* qrow = qacc + (size_t)(rowbase + (T << 6) + q_loc) * DIMS + col0;
#pragma unroll
            for (int kb = 0; kb < 2; ++kb) {
                float4 x0 = ld4(qrow + (kb << 5) + (g4 << 3));
                float4 x1 = ld4(qrow + (kb << 5) + (g4 << 3) + 4);
                unsigned hws[4], lws[4];
                split_pair(x0.x, x0.y, hws[0], lws[0]);
                split_pair(x0.z, x0.w, hws[1], lws[1]);
                split_pair(x1.x, x1.y, hws[2], lws[2]);
                split_pair(x1.z, x1.w, hws[3], lws[3]);
#pragma unroll
                for (int p2 = 0; p2 < 4; ++p2) {
                    reinterpret_cast<unsigned*>(&bqh[kb])[p2] = hws[p2];
                    reinterpret_cast<unsigned*>(&bql[kb])[p2] = lws[p2];
                }
            }
        }
        f32x4 qpa[4] = {{0,0,0,0},{0,0,0,0},{0,0,0,0},{0,0,0,0}};
        __builtin_amdgcn_s_setprio(1);
#pragma unroll
        for (int jt = 0; jt < 4; ++jt) {
            int arow = (jt << 4) + qcol;
#pragma unroll
            for (int kb = 0; kb < 2; ++kb) {
                bf16x8 ah = *reinterpret_cast<const bf16x8*>(&kh[arow][(kb << 5) + (g4 << 3)]);
                bf16x8 al = *reinterpret_cast<const bf16x8*>(&kl[arow][(kb << 5) + (g4 << 3)]);
                qpa[jt] = __builtin_amdgcn_mfma_f32_16x16x32_bf16(ah, bqh[kb], qpa[jt], 0, 0, 0);
                qpa[jt] = __builtin_amdgcn_mfma_f32_16x16x32_bf16(al, bqh[kb], qpa[jt], 0, 0, 0);
                qpa[jt] = __builtin_amdgcn_mfma_f32_16x16x32_bf16(ah, bql[kb], qpa[jt], 0, 0, 0);
            }
        }
        __builtin_amdgcn_s_setprio(0);

        float vals[16];
        float s1 = 0.0f;
#pragma unroll
        for (int jt = 0; jt < 4; ++jt) {
            float4 b4 = ld4(lqb + (jt << 4) + (g4 << 2));
            const float* b4p = reinterpret_cast<const float*>(&b4);
#pragma unroll
            for (int r = 0; r < 4; ++r) {
                float v = qpa[jt][r] + b4p[r];
                vals[(jt << 2) + r] = v;
                s1 += v;
            }
        }
        s1 += __shfl_xor(s1, 16, 64);
        s1 += __shfl_xor(s1, 32, 64);
        float mean = s1 * (1.0f / 64.0f);
        float s2 = 0.0f;
#pragma unroll
        for (int e = 0; e < 16; ++e) { float d = vals[e] - mean; vals[e] = d; s2 += d * d; }
        s2 += __shfl_xor(s2, 16, 64);
        s2 += __shfl_xor(s2, 32, 64);
        float inv = rsqrtf(s2 * (1.0f / 64.0f) + LNEPS);
#pragma unroll
        for (int jt = 0; jt < 4; ++jt) {
            float4 w4 = ld4(lnw + (jt << 4) + (g4 << 2));
            const float* w4p = reinterpret_cast<const float*>(&w4);
#pragma unroll
            for (int r = 0; r < 4; ++r) vals[(jt << 2) + r] *= inv * w4p[r];
        }

        unsigned hw[8], lw[8];
#pragma unroll
        for (int jt = 0; jt < 4; ++jt) {
            split_pair(vals[(jt << 2) + 0], vals[(jt << 2) + 1], hw[(jt << 1) + 0], lw[(jt << 1) + 0]);
            split_pair(vals[(jt << 2) + 2], vals[(jt << 2) + 3], hw[(jt << 1) + 1], lw[(jt << 1) + 1]);
        }
#pragma unroll
        for (int kb = 0; kb < 2; ++kb)
#pragma unroll
            for (int ip = 0; ip < 4; ++ip) {
                int srcl = (((g4 & 1) << 1) + (ip >> 1)) * 16 + qcol;
                unsigned hA = __shfl(hw[(kb << 2) + (ip & 1)], srcl, 64);
                unsigned hB = __shfl(hw[(kb << 2) + 2 + (ip & 1)], srcl, 64);
                unsigned lA = __shfl(lw[(kb << 2) + (ip & 1)], srcl, 64);
                unsigned lB = __shfl(lw[(kb << 2) + 2 + (ip & 1)], srcl, 64);
                reinterpret_cast<unsigned*>(&qfh[ti][kb])[ip] = selhi ? hB : hA;
                reinterpret_cast<unsigned*>(&qfl[ti][kb])[ip] = selhi ? lB : lA;
            }
    }
    __syncthreads();   // phase-A LDS reads done; planes free for K/V

    // ---- flash loop over chunks (both tiles share staged K/V) ----
    float m_r[2] = {-INFINITY, -INFINITY}, l_r[2] = {0.0f, 0.0f};
    f32x4 oacc[2][4] = {};

    for (int c = 0; c <= tHi; ++c) {
#pragma unroll
        for (int rr = 0; rr < 4; ++rr) {
            int row = (wv << 4) + (rr << 2) + g4;
            uint4 pk = kpre[rr];
            unsigned* khp = reinterpret_cast<unsigned*>(&kh[row][qcol << 2]);
            khp[0] = __byte_perm(pk.x, pk.y, 0x7632);
            khp[1] = __byte_perm(pk.z, pk.w, 0x7632);
            unsigned* klp = reinterpret_cast<unsigned*>(&kl[row][qcol << 2]);
            klp[0] = __byte_perm(pk.x, pk.y, 0x5410);
            klp[1] = __byte_perm(pk.z, pk.w, 0x5410);
            uint4 pv = vpre[rr];
            unsigned* vhp = reinterpret_cast<unsigned*>(&vh[row][qcol << 2]);
            vhp[0] = __byte_perm(pv.x, pv.y, 0x7632);
            vhp[1] = __byte_perm(pv.z, pv.w, 0x7632);
            unsigned* vlp = reinterpret_cast<unsigned*>(&vl[row][qcol << 2]);
            vlp[0] = __byte_perm(pv.x, pv.y, 0x5410);
            vlp[1] = __byte_perm(pv.z, pv.w, 0x5410);
        }
        if (c < tHi) {
            const unsigned* ksrc = kbase + (((size_t)(c + 1) * 64) << 6);
            const unsigned* vsrc = vbase + (((size_t)(c + 1)) << 12);
#pragma unroll
            for (int rr = 0; rr < 4; ++rr) {
                int row = (wv << 4) + (rr << 2) + g4;
                kpre[rr] = *reinterpret_cast<const uint4*>(ksrc + ((size_t)row << 6) + (qcol << 2));
                vpre[rr] = *reinterpret_cast<const uint4*>(vsrc + ((size_t)row << 6) + (qcol << 2));
            }
        }
        __syncthreads();

#pragma unroll
        for (int ti = 0; ti < 2; ++ti) {
            if (ti == 0 || c <= tLo) {      // wave-uniform predicate
                int T = ti ? tLo : tHi;

                f32x4 sacc[4] = {{0,0,0,0},{0,0,0,0},{0,0,0,0},{0,0,0,0}};
                __builtin_amdgcn_s_setprio(1);
#pragma unroll
                for (int jt = 0; jt < 4; ++jt) {
                    int jrow = (jt << 4) + qcol;
#pragma unroll
                    for (int kb = 0; kb < 2; ++kb) {
                        bf16x8 ah = *reinterpret_cast<const bf16x8*>(&kh[jrow][(kb << 5) + (g4 << 3)]);
                        bf16x8 al = *reinterpret_cast<const bf16x8*>(&kl[jrow][(kb << 5) + (g4 << 3)]);
                        sacc[jt] = __builtin_amdgcn_mfma_f32_16x16x32_bf16(ah, qfh[ti][kb], sacc[jt], 0, 0, 0);
                        sacc[jt] = __builtin_amdgcn_mfma_f32_16x16x32_bf16(al, qfh[ti][kb], sacc[jt], 0, 0, 0);
                        sacc[jt] = __builtin_amdgcn_mfma_f32_16x16x32_bf16(ah, qfl[ti][kb], sacc[jt], 0, 0, 0);
                    }
                }
                __builtin_amdgcn_s_setprio(0);

                float sv[16];
                float mx = -3.0e38f;
#pragma unroll
                for (int jt = 0; jt < 4; ++jt)
#pragma unroll
                    for (int r = 0; r < 4; ++r) {
                        float s = sacc[jt][r] * 0.125f;
                        if (c == T) {
                            int j_loc = (jt << 4) + (g4 << 2) + r;
                            if (j_loc > q_loc) s = -3.0e38f;
                        }
                        sv[(jt << 2) + r] = s;
                        mx = fmaxf(mx, s);
                    }
                mx = fmaxf(mx, __shfl_xor(mx, 16, 64));
                mx = fmaxf(mx, __shfl_xor(mx, 32, 64));
                if (!__all(mx <= m_r[ti] + 8.0f)) {
                    float mnew = fmaxf(m_r[ti], mx);
                    float ef = __expf(m_r[ti] - mnew);
                    l_r[ti] *= ef;
#pragma unroll
                    for (int dt = 0; dt < 4; ++dt) oacc[ti][dt] *= ef;
                    m_r[ti] = mnew;
                }
                float ps = 0.0f;
#pragma unroll
                for (int e = 0; e < 16; ++e) {
                    float p = __expf(sv[e] - m_r[ti]);
                    sv[e] = p;
                    ps += p;
                }
                ps += __shfl_xor(ps, 16, 64);
                ps += __shfl_xor(ps, 32, 64);
                l_r[ti] += ps;

                unsigned hwp[8], lwp[8];
#pragma unroll
                for (int jt = 0; jt < 4; ++jt) {
                    split_pair(sv[(jt << 2) + 0], sv[(jt << 2) + 1], hwp[(jt << 1) + 0], lwp[(jt << 1) + 0]);
                    split_pair(sv[(jt << 2) + 2], sv[(jt << 2) + 3], hwp[(jt << 1) + 1], lwp[(jt << 1) + 1]);
                }

                __builtin_amdgcn_s_setprio(1);
#pragma unroll
                for (int kb2 = 0; kb2 < 2; ++kb2) {
                    bf16x8 ph, pl;
#pragma unroll
                    for (int ip = 0; ip < 4; ++ip) {
                        int srcl = (((g4 & 1) << 1) + (ip >> 1)) * 16 + qcol;
                        unsigned hA = __shfl(hwp[(kb2 << 2) + (ip & 1)], srcl, 64);
                        unsigned hB = __shfl(hwp[(kb2 << 2) + 2 + (ip & 1)], srcl, 64);
                        unsigned lA = __shfl(lwp[(kb2 << 2) + (ip & 1)], srcl, 64);
                        unsigned lB = __shfl(lwp[(kb2 << 2) + 2 + (ip & 1)], srcl, 64);
                        reinterpret_cast<unsigned*>(&ph)[ip] = selhi ? hB : hA;
                        reinterpret_cast<unsigned*>(&pl)[ip] = selhi ? lB : lA;
                    }
#pragma unroll
                    for (int dt = 0; dt < 4; ++dt) {
                        int drow = (dt << 4) + qcol;
                        bf16x8 ah = *reinterpret_cast<const bf16x8*>(&vh[drow][(kb2 << 5) + (g4 << 3)]);
                        bf16x8 al = *reinterpret_cast<const bf16x8*>(&vl[drow][(kb2 << 5) + (g4 << 3)]);
                        oacc[ti][dt] = __builtin_amdgcn_mfma_f32_16x16x32_bf16(ah, ph, oacc[ti][dt], 0, 0, 0);
                        oacc[ti][dt] = __builtin_amdgcn_mfma_f32_16x16x32_bf16(al, ph, oacc[ti][dt], 0, 0, 0);
                        oacc[ti][dt] = __builtin_amdgcn_mfma_f32_16x16x32_bf16(ah, pl, oacc[ti][dt], 0, 0, 0);
                    }
                }
                __builtin_amdgcn_s_setprio(0);
            }
        }
        __syncthreads();   // all LDS reads done before next chunk's staging
    }

    // ---- epilogue (both tiles) ----
    float dsum = 0.0f;
#pragma unroll
    for (int ti = 0; ti < 2; ++ti) {
        int T = ti ? tLo : tHi;
        float invl = 1.0f / l_r[ti];
        float* orow = o_io + (size_t)(rowbase + (T << 6) + q_loc) * DIMS + col0;
#pragma unroll
        for (int dt = 0; dt < 4; ++dt) {
            float4 ov = make_float4(oacc[ti][dt][0] * invl, oacc[ti][dt][1] * invl,
                                    oacc[ti][dt][2] * invl, oacc[ti][dt][3] * invl);
            float* addr = orow + (dt << 4) + (g4 << 2);
            if (DIFF) {
                float4 pv4 = ld4(addr);
                dsum += fabsf(ov.x - pv4.x) + fabsf(ov.y - pv4.y)
                      + fabsf(ov.z - pv4.z) + fabsf(ov.w - pv4.w);
            }
            st4(addr, ov);
        }
    }
    if (DIFF) {
        float s = wave_sum64(dsum);
        if (lane == 0) dred[wv] = s;
        __syncthreads();
        if (tid == 0) {
            double tot = (double)(dred[0] + dred[1] + dred[2] + dred[3]);
            unsigned long long q = (unsigned long long)(tot * FIXSCALE + 0.5);
            atomicAdd(&diff_acc[w], q);
        }
    }
}

// -------- qacc[u,:] += scramble(o)[u,:]  (torch q_cur += iter_out) -----------
__global__ __launch_bounds__(256)
void scatter_add_kernel(float* __restrict__ qacc, const float* __restrict__ o) {
    size_t gid = (size_t)blockIdx.x * 256 + threadIdx.x;
    size_t flat = gid << 2;
    int uu = (int)(flat >> 6);
    int col = (int)(flat & 63);
    int r = uu >> 4, h = uu & 15;
    int s = r & 511;
    int rb = r - s;
    size_t src = ((size_t)(rb + h * 32 + (s >> 4)) << 10)
               + (size_t)((s & 15) << 6) + col;
    float4 a = ld4(qacc + flat);
    float4 bv = ld4(o + src);
    st4(qacc + flat, make_float4(a.x + bv.x, a.y + bv.y, a.z + bv.z, a.w + bv.w));
}

__global__ void init_ctrl_kernel(unsigned long long* __restrict__ dacc,
                                 int* __restrict__ conv) {
    int i = threadIdx.x;
    if (i < 8) { dacc[i] = 0ULL; conv[i] = 0; }
}

__global__ void conv_from_acc_kernel(const unsigned long long* __restrict__ dacc,
                                     int* __restrict__ conv) {
    int w = threadIdx.x;
    if (w < 8) {
        float mean = (float)((double)dacc[w] * (1.0 / (FIXSCALE * 2097152.0)));
        conv[w] = (mean < 0.01f + 0.1f * mean) ? 1 : 0;
    }
}

// -------- unscramble src into SPLIT hi/lo preout planes ----------------------
__global__ __launch_bounds__(256)
void unscramble_split_kernel(const float* __restrict__ src, unsigned short* __restrict__ hp,
                             unsigned short* __restrict__ lp) {
    size_t gid = (size_t)blockIdx.x * 256 + threadIdx.x;
    size_t flat = gid << 2;
    int r = (int)(flat >> 10);
    int e = (int)(flat & 1023);
    int h2 = e >> 6, d2 = e & 63;
    int s2 = r & 511;
    int rb = r - s2;
    size_t sidx = ((size_t)(rb + h2 * 32 + (s2 >> 4)) << 10) + (size_t)((s2 & 15) << 6) + d2;
    float4 v = ld4(src + sidx);
    unsigned h0, l0, h1, l1;
    split_pair(v.x, v.y, h0, l0);
    split_pair(v.z, v.w, h1, l1);
    *reinterpret_cast<uint2*>(hp + flat) = make_uint2(h0, h1);
    *reinterpret_cast<uint2*>(lp + flat) = make_uint2(l0, l1);
}

extern "C" void kernel_launch(void* const* d_in, const int* in_sizes, int n_in,
                              void* d_out, int out_size, void* d_ws, size_t ws_size,
                              hipStream_t stream) {
    (void)in_sizes; (void)n_in; (void)out_size; (void)ws_size;
    const float* x   = (const float*)d_in[0];
    const float* Wq  = (const float*)d_in[1];
    const float* bq  = (const float*)d_in[2];
    const float* Wk  = (const float*)d_in[3];
    const float* Wv  = (const float*)d_in[4];
    const float* bv  = (const float*)d_in[5];
    const float* Wo  = (const float*)d_in[6];
    const float* bo  = (const float*)d_in[7];
    const float* lna = (const float*)d_in[8];
    const float* lnb = (const float*)d_in[9];
    const float* lqw = (const float*)d_in[10];
    const float* lqb = (const float*)d_in[11];
    const float* lkw = (const float*)d_in[12];
    const float* lkb = (const float*)d_in[13];
    const float* lvw = (const float*)d_in[14];
    const float* lvb = (const float*)d_in[15];

    // ws: [4 KiB ctrl][R1][R2][R3] = 192 MiB + 4 KiB (proven bound).
    // R1: qacc f32 -> (end) Wo split planes. R2: xn split planes -> khl -> preout planes.
    // R3: Wq/Wk split scratch -> v f32 -> o. E(d_out): k f32 -> vthl -> final out.
    const size_t BUF = (size_t)NROWS * DIMS;      // 16M elements
    unsigned long long* dacc = (unsigned long long*)d_ws;
    int* conv = (int*)(dacc + 8);
    float* R1 = (float*)((char*)d_ws + 4096);
    float* R2 = R1 + BUF;
    float* R3 = R2 + BUF;
    float* E  = (float*)d_out;

    unsigned short* XNH = (unsigned short*)R2;        // 32 MiB
    unsigned short* XNL = XNH + BUF;                  // 32 MiB
    unsigned short* WSH = (unsigned short*)R3;        // 2 MiB W-split scratch
    unsigned short* WSL = WSH + (size_t)DIMS * DIMS;  // 2 MiB
    unsigned short* WOH = (unsigned short*)R1;        // Wo planes (qacc dead by then)
    unsigned short* WOL = WOH + (size_t)DIMS * DIMS;
    unsigned short* PH  = (unsigned short*)R2;        // preout planes (khl dead)
    unsigned short* PL  = PH + BUF;

    const float scale = 0.35355339059327373f;     // 64^-0.25
    const int WGRID = DIMS * DIMS / 4 / 256;      // 1024 blocks

    // 1. xn hi/lo planes -> R2
    ln1024_split_kernel<<<NROWS, 256, 0, stream>>>(x, lna, XNH, XNL);

    // 2. GEMMs. Q,K use pre-split W in R3 scratch; V splits on the fly.
    dim3 gg(NROWS / 128, DIMS / 128);
    presplit_w_kernel<<<WGRID, 256, 0, stream>>>(Wq, WSH, WSL);
    gemm_hl_kernel<1, 1><<<gg, 256, 0, stream>>>(XNH, XNL, nullptr, WSH, WSL, bq, R1, scale, 1, lnb);
    presplit_w_kernel<<<WGRID, 256, 0, stream>>>(Wk, WSH, WSL);
    gemm_hl_kernel<1, 1><<<gg, 256, 0, stream>>>(XNH, XNL, nullptr, WSH, WSL, bq, E, scale, 0, lnb);
    gemm_hl_kernel<0, 0><<<gg, 256, 0, stream>>>(XNH, XNL, Wv, nullptr, nullptr, bv, R3, 1.0f, 1, lnb);

    // 3. kp plane (xn planes dead): E -> R2 ; vt plane (k dead): R3 -> E
    proj64_khl_kernel<<<NUNITS / 64, 256, 0, stream>>>(E, lkw, lkb, lnb, (unsigned*)R2);
    proj64_vthl_kernel<<<NUNITS / 64, 256, 0, stream>>>(R3, lvw, lvb, (unsigned*)E);

    // 4. control init
    init_ctrl_kernel<<<1, 64, 0, stream>>>(dacc, conv);

    const unsigned* KHL = (const unsigned*)R2;
    const unsigned* VTHL = (const unsigned*)E;

    // 5. it 0: o0 -> R3 (v f32 dead); 2048 blocks = 4 tile-pairs x 512 units
    attn_mfma_kernel<0, 0><<<512 * 4, 256, 0, stream>>>(R1, KHL, VTHL, R3, lqw, lqb, lnb, dacc, conv);
    // 6. qacc += scr(o0)
    scatter_add_kernel<<<NROWS * DIMS / 4 / 256, 256, 0, stream>>>(R1, R3);
    // 7. it 1: o1 -> R3 in place, fused per-window diff vs o0
    attn_mfma_kernel<1, 0><<<512 * 4, 256, 0, stream>>>(R1, KHL, VTHL, R3, lqw, lqb, lnb, dacc, conv);
    // 8. conv flags
    conv_from_acc_kernel<<<1, 64, 0, stream>>>(dacc, conv);
    // 9. qacc += scr(o1)
    scatter_add_kernel<<<NROWS * DIMS / 4 / 256, 256, 0, stream>>>(R1, R3);
    // 10. it 2: o2 -> R3, skipped for converged windows (keeps o1)
    attn_mfma_kernel<0, 1><<<512 * 4, 256, 0, stream>>>(R1, KHL, VTHL, R3, lqw, lqb, lnb, dacc, conv);

    // 11. preout planes = split(unscramble(R3)) -> R2 (khl dead)
    unscramble_split_kernel<<<NROWS * DIMS / 4 / 256, 256, 0, stream>>>(R3, PH, PL);
    // 12. Wo planes -> R1 (qacc dead); out = preout @ Wo^T + bo -> d_out (vthl dead)
    presplit_w_kernel<<<WGRID, 256, 0, stream>>>(Wo, WOH, WOL);
    gemm_hl_kernel<0, 1><<<gg, 256, 0, stream>>>(PH, PL, nullptr, WOH, WOL, bo, (float*)d_out, 1.0f, 1, lnb);
}

// Round 13
// 1002.251 us; speedup vs baseline: 1.4541x; 1.4541x over previous
//
#include <hip/hip_runtime.h>
#include <math.h>

// Problem constants (from reference)
#define DIMS   1024
#define NHEAD  16
#define HD     64
#define WIN    512
#define CTX    4096
#define NBATCH 4
#define NROWS  (NBATCH*CTX)        // 16384 total sequence rows
#define NUNITS (NROWS*NHEAD)       // 262144 (row,head) units
#define LNEPS  1e-5f
#define FIXSCALE 16777216.0        // 2^24 fixed-point for deterministic diff

typedef __attribute__((ext_vector_type(8))) short bf16x8;   // 8 bf16 (4 VGPR)
typedef __attribute__((ext_vector_type(4))) float f32x4;    // MFMA C/D

__device__ __forceinline__ float4 ld4(const float* p) { return *reinterpret_cast<const float4*>(p); }
__device__ __forceinline__ void st4(float* p, float4 v) { *reinterpret_cast<float4*>(p) = v; }

__device__ __forceinline__ float wave_sum64(float v) {
#pragma unroll
    for (int off = 32; off; off >>= 1) v += __shfl_xor(v, off, 64);
    return v;
}
__device__ __forceinline__ float grp16_sum(float v) {
    v += __shfl_xor(v, 1, 64);
    v += __shfl_xor(v, 2, 64);
    v += __shfl_xor(v, 4, 64);
    v += __shfl_xor(v, 8, 64);
    return v;
}

// round-to-nearest-even bf16 of x, packed split: (hi<<16)|lo with hi+lo ~= x (err ~2^-17)
__device__ __forceinline__ unsigned bf16_rn_bits(float x) {
    unsigned u = __float_as_uint(x);
    return (u + 0x7fffu + ((u >> 16) & 1u)) >> 16;
}
__device__ __forceinline__ unsigned pack_hl(float x) {
    unsigned h = bf16_rn_bits(x);
    float hf = __uint_as_float(h << 16);
    unsigned l = bf16_rn_bits(x - hf);
    return (h << 16) | (l & 0xffffu);
}

// v_cvt_pk_bf16_f32: D[15:0]=bf16(a), D[31:16]=bf16(b)  (T12 recipe)
__device__ __forceinline__ unsigned cvtpk_bf16(float a, float b) {
    unsigned r;
    asm volatile("v_cvt_pk_bf16_f32 %0, %1, %2" : "=v"(r) : "v"(a), "v"(b));
    return r;
}
__device__ __forceinline__ void split_pair(float a, float b, unsigned& hw, unsigned& lw) {
    hw = cvtpk_bf16(a, b);
    float ha = __uint_as_float(hw << 16);
    float hb = __uint_as_float(hw & 0xffff0000u);
    lw = cvtpk_bf16(a - ha, b - hb);
}

// XOR-swizzled byte offset into a [rows][64] short LDS plane (stride 128 B)
__device__ __forceinline__ int swzo(int row, int kbyte) {
    return ((row << 7) + kbyte) ^ ((row & 7) << 4);
}

// -------- LayerNorm over D=1024 (row-wise), PACKED hi/lo output --------------
__global__ __launch_bounds__(256)
void ln1024_pack_kernel(const float* __restrict__ x, const float* __restrict__ w,
                        unsigned* __restrict__ outp) {
    int r = blockIdx.x;
    int tid = threadIdx.x;
    const float* xr = x + (size_t)r * DIMS;
    float4 v = ld4(xr + (tid << 2));
    __shared__ float red[8];
    float s = wave_sum64(v.x + v.y + v.z + v.w);
    int wv = tid >> 6, lane = tid & 63;
    if (lane == 0) red[wv] = s;
    __syncthreads();
    float mean = (red[0] + red[1] + red[2] + red[3]) * (1.0f / DIMS);
    float dx = v.x - mean, dy = v.y - mean, dz = v.z - mean, dw = v.w - mean;
    float ss = wave_sum64(dx*dx + dy*dy + dz*dz + dw*dw);
    if (lane == 0) red[4 + wv] = ss;
    __syncthreads();
    float inv = rsqrtf((red[4] + red[5] + red[6] + red[7]) * (1.0f / DIMS) + LNEPS);
    float4 wv4 = ld4(w + (tid << 2));
    uint4 pk;
    pk.x = pack_hl(dx * inv * wv4.x);
    pk.y = pack_hl(dy * inv * wv4.y);
    pk.z = pack_hl(dz * inv * wv4.z);
    pk.w = pack_hl(dw * inv * wv4.w);
    *reinterpret_cast<uint4*>(outp + (size_t)r * DIMS + (tid << 2)) = pk;
}

// -------- bf16 hi/lo 3-term MFMA GEMM (optional fused per-head LN) -----------
// A packed-hl u32 stream (single stream, L2-friendly); W f32 split on the fly
// via cvt_pk (split_pair) — only change vs the proven R9 kernel.
template<int DO_HLN>
__global__ __launch_bounds__(256, 2)
void gemm_hl_kernel(const unsigned* __restrict__ Ahl, const float* __restrict__ W,
                    const float* __restrict__ bias, float* __restrict__ Cm,
                    float alpha, int has_bias, const float* __restrict__ lnw) {
    __shared__ short Ah[128 * 64], Al[128 * 64], Wh[128 * 64], Wl[128 * 64]; // 64 KiB
    int tid = threadIdx.x;
    int wid = tid >> 6, lane = tid & 63;
    int wm = (wid >> 1) << 6, wn = (wid & 1) << 6;
    int g4 = lane >> 4, l16 = lane & 15;
    int m0 = blockIdx.x << 7, n0 = blockIdx.y << 7;

    f32x4 acc[4][4] = {};

    int orow[4], okb[4];
#pragma unroll
    for (int j = 0; j < 4; ++j) {
        int oc = tid + (j << 8);
        orow[j] = oc >> 3;
        okb[j] = (oc & 7) << 4;
    }

    for (int k0 = 0; k0 < 1024; k0 += 64) {
        uint4 a0[4], a1[4];
        float4 w0[4], w1[4];
#pragma unroll
        for (int j = 0; j < 4; ++j) {
            const unsigned* ap = Ahl + (size_t)(m0 + orow[j]) * 1024 + k0 + (okb[j] >> 1);
            a0[j] = *reinterpret_cast<const uint4*>(ap);
            a1[j] = *reinterpret_cast<const uint4*>(ap + 4);
            const float* wp = W + (size_t)(n0 + orow[j]) * 1024 + k0 + (okb[j] >> 1);
            w0[j] = *reinterpret_cast<const float4*>(wp);
            w1[j] = *reinterpret_cast<const float4*>(wp + 4);
        }
        __syncthreads();   // prior iteration's fragment reads complete
#pragma unroll
        for (int j = 0; j < 4; ++j) {
            int off = swzo(orow[j], okb[j]);
            uint4 hi, lo;
            hi.x = __byte_perm(a0[j].x, a0[j].y, 0x7632);
            hi.y = __byte_perm(a0[j].z, a0[j].w, 0x7632);
            hi.z = __byte_perm(a1[j].x, a1[j].y, 0x7632);
            hi.w = __byte_perm(a1[j].z, a1[j].w, 0x7632);
            lo.x = __byte_perm(a0[j].x, a0[j].y, 0x5410);
            lo.y = __byte_perm(a0[j].z, a0[j].w, 0x5410);
            lo.z = __byte_perm(a1[j].x, a1[j].y, 0x5410);
            lo.w = __byte_perm(a1[j].z, a1[j].w, 0x5410);
            *reinterpret_cast<uint4*>(reinterpret_cast<char*>(Ah) + off) = hi;
            *reinterpret_cast<uint4*>(reinterpret_cast<char*>(Al) + off) = lo;

            uint4 hw4, lw4;
            split_pair(w0[j].x, w0[j].y, hw4.x, lw4.x);
            split_pair(w0[j].z, w0[j].w, hw4.y, lw4.y);
            split_pair(w1[j].x, w1[j].y, hw4.z, lw4.z);
            split_pair(w1[j].z, w1[j].w, hw4.w, lw4.w);
            *reinterpret_cast<uint4*>(reinterpret_cast<char*>(Wh) + off) = hw4;
            *reinterpret_cast<uint4*>(reinterpret_cast<char*>(Wl) + off) = lw4;
        }
        __syncthreads();

#pragma unroll
        for (int kk = 0; kk < 2; ++kk) {
            bf16x8 afh[4], afl[4], wfh[4], wfl[4];
#pragma unroll
            for (int mt = 0; mt < 4; ++mt) {
                int row = wm + (mt << 4) + l16;
                int off = ((row << 7) + (kk << 6) + (g4 << 4)) ^ ((row & 7) << 4);
                afh[mt] = *reinterpret_cast<const bf16x8*>(reinterpret_cast<const char*>(Ah) + off);
                afl[mt] = *reinterpret_cast<const bf16x8*>(reinterpret_cast<const char*>(Al) + off);
            }
#pragma unroll
            for (int nt = 0; nt < 4; ++nt) {
                int row = wn + (nt << 4) + l16;
                int off = ((row << 7) + (kk << 6) + (g4 << 4)) ^ ((row & 7) << 4);
                wfh[nt] = *reinterpret_cast<const bf16x8*>(reinterpret_cast<const char*>(Wh) + off);
                wfl[nt] = *reinterpret_cast<const bf16x8*>(reinterpret_cast<const char*>(Wl) + off);
            }
#pragma unroll
            for (int mt = 0; mt < 4; ++mt)
#pragma unroll
                for (int nt = 0; nt < 4; ++nt) {
                    acc[mt][nt] = __builtin_amdgcn_mfma_f32_16x16x32_bf16(afh[mt], wfh[nt], acc[mt][nt], 0, 0, 0);
                    acc[mt][nt] = __builtin_amdgcn_mfma_f32_16x16x32_bf16(afl[mt], wfh[nt], acc[mt][nt], 0, 0, 0);
                    acc[mt][nt] = __builtin_amdgcn_mfma_f32_16x16x32_bf16(afh[mt], wfl[nt], acc[mt][nt], 0, 0, 0);
                }
        }
    }

    if (DO_HLN) {
        float bb[4];
#pragma unroll
        for (int nt = 0; nt < 4; ++nt)
            bb[nt] = has_bias ? bias[n0 + wn + (nt << 4) + l16] : 0.0f;
        float lw4[4];
#pragma unroll
        for (int nt = 0; nt < 4; ++nt) lw4[nt] = lnw[(nt << 4) + l16];
#pragma unroll
        for (int mt = 0; mt < 4; ++mt)
#pragma unroll
            for (int r = 0; r < 4; ++r) {
                float v[4];
                float s1 = 0.0f;
#pragma unroll
                for (int nt = 0; nt < 4; ++nt) {
                    v[nt] = alpha * (acc[mt][nt][r] + bb[nt]);
                    s1 += v[nt];
                }
                s1 = grp16_sum(s1);
                float mean = s1 * (1.0f / 64.0f);
                float s2 = 0.0f;
#pragma unroll
                for (int nt = 0; nt < 4; ++nt) { v[nt] -= mean; s2 += v[nt] * v[nt]; }
                s2 = grp16_sum(s2);
                float inv = rsqrtf(s2 * (1.0f / 64.0f) + LNEPS);
                int row = m0 + wm + (mt << 4) + (g4 << 2) + r;
#pragma unroll
                for (int nt = 0; nt < 4; ++nt)
                    Cm[(size_t)row * DIMS + n0 + wn + (nt << 4) + l16] = v[nt] * inv * lw4[nt];
            }
    } else {
#pragma unroll
        for (int mt = 0; mt < 4; ++mt)
#pragma unroll
            for (int nt = 0; nt < 4; ++nt) {
                int col = n0 + wn + (nt << 4) + l16;
                float bb = has_bias ? bias[col] : 0.0f;
#pragma unroll
                for (int r = 0; r < 4; ++r) {
                    int row = m0 + wm + (mt << 4) + (g4 << 2) + r;
                    Cm[(size_t)row * DIMS + col] = alpha * (acc[mt][nt][r] + bb);
                }
            }
    }
}

// -------- kp projection + LN + hi/lo split -> packed K plane -----------------
__global__ __launch_bounds__(256)
void proj64_khl_kernel(const float* __restrict__ inp, const float* __restrict__ W,
                       const float* __restrict__ Wb, const float* __restrict__ lnw,
                       unsigned* __restrict__ plane) {
    int u0 = blockIdx.x << 6;
    __shared__ float As[64][68];
    __shared__ float Bs[64][68];
    int tid = threadIdx.x;
    for (int e = tid; e < 4096; e += 256) Bs[e & 63][e >> 6] = W[e];
    for (int e = tid; e < 1024; e += 256) {
        int row = e >> 4;
        int col = (e & 15) << 2;
        float4 v = ld4(inp + ((size_t)(u0 + row) << 6) + col);
        As[col + 0][row] = v.x; As[col + 1][row] = v.y;
        As[col + 2][row] = v.z; As[col + 3][row] = v.w;
    }
    __syncthreads();
    int tm = tid >> 4, tn = tid & 15;
    float acc[4][4] = {};
#pragma unroll
    for (int k = 0; k < 64; ++k) {
        float4 av = ld4(&As[k][tm << 2]);
        float4 bv = ld4(&Bs[k][tn << 2]);
        float aa[4] = {av.x, av.y, av.z, av.w};
        float bb[4] = {bv.x, bv.y, bv.z, bv.w};
#pragma unroll
        for (int mm = 0; mm < 4; ++mm)
#pragma unroll
            for (int nn = 0; nn < 4; ++nn)
                acc[mm][nn] = fmaf(aa[mm], bb[nn], acc[mm][nn]);
    }
    float bb4[4] = {Wb[(tn << 2) + 0], Wb[(tn << 2) + 1], Wb[(tn << 2) + 2], Wb[(tn << 2) + 3]};
    float lw4[4] = {lnw[(tn << 2) + 0], lnw[(tn << 2) + 1], lnw[(tn << 2) + 2], lnw[(tn << 2) + 3]};
#pragma unroll
    for (int mm = 0; mm < 4; ++mm) {
        float o0 = acc[mm][0] + bb4[0], o1 = acc[mm][1] + bb4[1];
        float o2 = acc[mm][2] + bb4[2], o3 = acc[mm][3] + bb4[3];
        float mean = grp16_sum(o0 + o1 + o2 + o3) * (1.0f / 64.0f);
        float d0 = o0 - mean, d1 = o1 - mean, d2 = o2 - mean, d3 = o3 - mean;
        float var = grp16_sum(d0*d0 + d1*d1 + d2*d2 + d3*d3) * (1.0f / 64.0f);
        float inv = rsqrtf(var + LNEPS);
        o0 = d0 * inv * lw4[0]; o1 = d1 * inv * lw4[1];
        o2 = d2 * inv * lw4[2]; o3 = d3 * inv * lw4[3];
        int u_p = u0 + (tm << 2) + mm;
        int r = u_p >> 4, h = u_p & 15;
        int s = r & 511;
        int ua = ((r >> 9) << 4) + h;
        size_t punit = (size_t)ua * 512 + s;
        uint4 pk;
        pk.x = pack_hl(o0); pk.y = pack_hl(o1); pk.z = pack_hl(o2); pk.w = pack_hl(o3);
        *reinterpret_cast<uint4*>(plane + (punit << 6) + (tn << 2)) = pk;
    }
}

// -------- vp projection + hi/lo split -> packed transposed V plane -----------
__global__ __launch_bounds__(256)
void proj64_vthl_kernel(const float* __restrict__ inp, const float* __restrict__ W,
                        const float* __restrict__ Wb, unsigned* __restrict__ plane) {
    int u0 = blockIdx.x << 6;
    __shared__ float As[64][68];
    __shared__ float Bs[64][68];
    int tid = threadIdx.x;
    for (int e = tid; e < 4096; e += 256) Bs[e & 63][e >> 6] = W[e];
    for (int e = tid; e < 1024; e += 256) {
        int row = e >> 4;
        int col = (e & 15) << 2;
        float4 v = ld4(inp + ((size_t)(u0 + row) << 6) + col);
        As[col + 0][row] = v.x; As[col + 1][row] = v.y;
        As[col + 2][row] = v.z; As[col + 3][row] = v.w;
    }
    __syncthreads();
    int tm = tid >> 4, tn = tid & 15;
    float acc[4][4] = {};
#pragma unroll
    for (int k = 0; k < 64; ++k) {
        float4 av = ld4(&As[k][tm << 2]);
        float4 bv = ld4(&Bs[k][tn << 2]);
        float aa[4] = {av.x, av.y, av.z, av.w};
        float bb[4] = {bv.x, bv.y, bv.z, bv.w};
#pragma unroll
        for (int mm = 0; mm < 4; ++mm)
#pragma unroll
            for (int nn = 0; nn < 4; ++nn)
                acc[mm][nn] = fmaf(aa[mm], bb[nn], acc[mm][nn]);
    }
    float bb4[4] = {Wb[(tn << 2) + 0], Wb[(tn << 2) + 1], Wb[(tn << 2) + 2], Wb[(tn << 2) + 3]};
#pragma unroll
    for (int mm = 0; mm < 4; ++mm) {
        int u_p = u0 + (tm << 2) + mm;
        int r = u_p >> 4, h = u_p & 15;
        int s = r & 511;
        int ua = ((r >> 9) << 4) + h;
        size_t base = ((size_t)(ua * 8 + (s >> 6)) << 12) + (s & 63);
#pragma unroll
        for (int nn = 0; nn < 4; ++nn) {
            int d = (tn << 2) + nn;
            plane[base + ((size_t)d << 6)] = pack_hl(acc[mm][nn] + bb4[nn]);
        }
    }
}

// -------- fused MFMA attention: TWO q-tiles per block (EXACT R9 version) -----
template<int DIFF, int USE_CONV>
__global__ __launch_bounds__(256)
void attn_mfma_kernel(const float* __restrict__ qacc, const unsigned* __restrict__ khl,
                      const unsigned* __restrict__ vthl, float* __restrict__ o_io,
                      const float* __restrict__ lqw, const float* __restrict__ lqb,
                      const float* __restrict__ lnw,
                      unsigned long long* __restrict__ diff_acc,
                      const int* __restrict__ conv) {
    __shared__ short kh[64][72], kl[64][72], vh[64][72], vl[64][72];   // 36864 B
    __shared__ float dred[4];

    int blk = blockIdx.x;
    int u = blk & 511;
    int pr = blk >> 9;             // 0..3
    int tHi = 7 - (pr << 1);       // 7,5,3,1 (heavy pairs launch first)
    int tLo = tHi - 1;             // 6,4,2,0
    int h = u & 15;
    int w = (u >> 4) & 7;
    int b = u >> 7;
    if (USE_CONV && conv[w]) return;
    int rowbase = b * CTX + w * WIN;
    int col0 = h * HD;
    int tid = threadIdx.x;
    int wv = tid >> 6;
    int lane = tid & 63;
    int g4 = lane >> 4;
    int qcol = lane & 15;
    int q_loc = (wv << 4) + qcol;
    int selhi = g4 >> 1;

    const unsigned* kbase = khl + (((size_t)u * 512) << 6);
    const unsigned* vbase = vthl + (((size_t)u * 8) << 12);

    // ---- prefetch chunk 0 K,V (hides under phase A) ----
    uint4 kpre[4], vpre[4];
#pragma unroll
    for (int rr = 0; rr < 4; ++rr) {
        int row = (wv << 4) + (rr << 2) + g4;
        kpre[rr] = *reinterpret_cast<const uint4*>(kbase + ((size_t)row << 6) + (qcol << 2));
        vpre[rr] = *reinterpret_cast<const uint4*>(vbase + ((size_t)row << 6) + (qcol << 2));
    }

    // ---- phase A: stage lqw once; per tile qp^T = mfma(lqw, qacc^T) + LN ----
#pragma unroll
    for (int rr = 0; rr < 4; ++rr) {
        int row = (wv << 4) + (rr << 2) + g4;
        float4 v = ld4(lqw + (row << 6) + (qcol << 2));
        unsigned h0, l0, h1, l1;
        split_pair(v.x, v.y, h0, l0);
        split_pair(v.z, v.w, h1, l1);
        *reinterpret_cast<uint2*>(&kh[row][qcol << 2]) = make_uint2(h0, h1);
        *reinterpret_cast<uint2*>(&kl[row][qcol << 2]) = make_uint2(l0, l1);
    }
    __syncthreads();   // lqw staged

    bf16x8 qfh[2][2], qfl[2][2];   // [tile][kb]
#pragma unroll
    for (int ti = 0; ti < 2; ++ti) {
        int T = ti ? tLo : tHi;
        bf16x8 bqh[2], bql[2];
        {
            const float* qrow = qacc + (size_t)(rowbase + (T << 6) + q_loc) * DIMS + col0;
#pragma unroll
            for (int kb = 0; kb < 2; ++kb) {
                float4 x0 = ld4(qrow + (kb << 5) + (g4 << 3));
                float4 x1 = ld4(qrow + (kb << 5) + (g4 << 3) + 4);
                unsigned hws[4], lws[4];
                split_pair(x0.x, x0.y, hws[0], lws[0]);
                split_pair(x0.z, x0.w, hws[1], lws[1]);
                split_pair(x1.x, x1.y, hws[2], lws[2]);
                split_pair(x1.z, x1.w, hws[3], lws[3]);
#pragma unroll
                for (int p2 = 0; p2 < 4; ++p2) {
                    reinterpret_cast<unsigned*>(&bqh[kb])[p2] = hws[p2];
                    reinterpret_cast<unsigned*>(&bql[kb])[p2] = lws[p2];
                }
            }
        }
        f32x4 qpa[4] = {{0,0,0,0},{0,0,0,0},{0,0,0,0},{0,0,0,0}};
        __builtin_amdgcn_s_setprio(1);
#pragma unroll
        for (int jt = 0; jt < 4; ++jt) {
            int arow = (jt << 4) + qcol;
#pragma unroll
            for (int kb = 0; kb < 2; ++kb) {
                bf16x8 ah = *reinterpret_cast<const bf16x8*>(&kh[arow][(kb << 5) + (g4 << 3)]);
                bf16x8 al = *reinterpret_cast<const bf16x8*>(&kl[arow][(kb << 5) + (g4 << 3)]);
                qpa[jt] = __builtin_amdgcn_mfma_f32_16x16x32_bf16(ah, bqh[kb], qpa[jt], 0, 0, 0);
                qpa[jt] = __builtin_amdgcn_mfma_f32_16x16x32_bf16(al, bqh[kb], qpa[jt], 0, 0, 0);
                qpa[jt] = __builtin_amdgcn_mfma_f32_16x16x32_bf16(ah, bql[kb], qpa[jt], 0, 0, 0);
            }
        }
        __builtin_amdgcn_s_setprio(0);

        float vals[16];
        float s1 = 0.0f;
#pragma unroll
        for (int jt = 0; jt < 4; ++jt) {
            float4 b4 = ld4(lqb + (jt << 4) + (g4 << 2));
            const float* b4p = reinterpret_cast<const float*>(&b4);
#pragma unroll
            for (int r = 0; r < 4; ++r) {
                float v = qpa[jt][r] + b4p[r];
                vals[(jt << 2) + r] = v;
                s1 += v;
            }
        }
        s1 += __shfl_xor(s1, 16, 64);
        s1 += __shfl_xor(s1, 32, 64);
        float mean = s1 * (1.0f / 64.0f);
        float s2 = 0.0f;
#pragma unroll
        for (int e = 0; e < 16; ++e) { float d = vals[e] - mean; vals[e] = d; s2 += d * d; }
        s2 += __shfl_xor(s2, 16, 64);
        s2 += __shfl_xor(s2, 32, 64);
        float inv = rsqrtf(s2 * (1.0f / 64.0f) + LNEPS);
#pragma unroll
        for (int jt = 0; jt < 4; ++jt) {
            float4 w4 = ld4(lnw + (jt << 4) + (g4 << 2));
            const float* w4p = reinterpret_cast<const float*>(&w4);
#pragma unroll
            for (int r = 0; r < 4; ++r) vals[(jt << 2) + r] *= inv * w4p[r];
        }

        unsigned hw[8], lw[8];
#pragma unroll
        for (int jt = 0; jt < 4; ++jt) {
            split_pair(vals[(jt << 2) + 0], vals[(jt << 2) + 1], hw[(jt << 1) + 0], lw[(jt << 1) + 0]);
            split_pair(vals[(jt << 2) + 2], vals[(jt << 2) + 3], hw[(jt << 1) + 1], lw[(jt << 1) + 1]);
        }
#pragma unroll
        for (int kb = 0; kb < 2; ++kb)
#pragma unroll
            for (int ip = 0; ip < 4; ++ip) {
                int srcl = (((g4 & 1) << 1) + (ip >> 1)) * 16 + qcol;
                unsigned hA = __shfl(hw[(kb << 2) + (ip & 1)], srcl, 64);
                unsigned hB = __shfl(hw[(kb << 2) + 2 + (ip & 1)], srcl, 64);
                unsigned lA = __shfl(lw[(kb << 2) + (ip & 1)], srcl, 64);
                unsigned lB = __shfl(lw[(kb << 2) + 2 + (ip & 1)], srcl, 64);
                reinterpret_cast<unsigned*>(&qfh[ti][kb])[ip] = selhi ? hB : hA;
                reinterpret_cast<unsigned*>(&qfl[ti][kb])[ip] = selhi ? lB : lA;
            }
    }
    __syncthreads();   // phase-A LDS reads done; planes free for K/V

    // ---- flash loop over chunks (both tiles share staged K/V) ----
    float m_r[2] = {-INFINITY, -INFINITY}, l_r[2] = {0.0f, 0.0f};
    f32x4 oacc[2][4] = {};

    for (int c = 0; c <= tHi; ++c) {
#pragma unroll
        for (int rr = 0; rr < 4; ++rr) {
            int row = (wv << 4) + (rr << 2) + g4;
            uint4 pk = kpre[rr];
            unsigned* khp = reinterpret_cast<unsigned*>(&kh[row][qcol << 2]);
            khp[0] = __byte_perm(pk.x, pk.y, 0x7632);
            khp[1] = __byte_perm(pk.z, pk.w, 0x7632);
            unsigned* klp = reinterpret_cast<unsigned*>(&kl[row][qcol << 2]);
            klp[0] = __byte_perm(pk.x, pk.y, 0x5410);
            klp[1] = __byte_perm(pk.z, pk.w, 0x5410);
            uint4 pv = vpre[rr];
            unsigned* vhp = reinterpret_cast<unsigned*>(&vh[row][qcol << 2]);
            vhp[0] = __byte_perm(pv.x, pv.y, 0x7632);
            vhp[1] = __byte_perm(pv.z, pv.w, 0x7632);
            unsigned* vlp = reinterpret_cast<unsigned*>(&vl[row][qcol << 2]);
            vlp[0] = __byte_perm(pv.x, pv.y, 0x5410);
            vlp[1] = __byte_perm(pv.z, pv.w, 0x5410);
        }
        if (c < tHi) {
            const unsigned* ksrc = kbase + (((size_t)(c + 1) * 64) << 6);
            const unsigned* vsrc = vbase + (((size_t)(c + 1)) << 12);
#pragma unroll
            for (int rr = 0; rr < 4; ++rr) {
                int row = (wv << 4) + (rr << 2) + g4;
                kpre[rr] = *reinterpret_cast<const uint4*>(ksrc + ((size_t)row << 6) + (qcol << 2));
                vpre[rr] = *reinterpret_cast<const uint4*>(vsrc + ((size_t)row << 6) + (qcol << 2));
            }
        }
        __syncthreads();

#pragma unroll
        for (int ti = 0; ti < 2; ++ti) {
            if (ti == 0 || c <= tLo) {      // wave-uniform predicate
                int T = ti ? tLo : tHi;

                f32x4 sacc[4] = {{0,0,0,0},{0,0,0,0},{0,0,0,0},{0,0,0,0}};
                __builtin_amdgcn_s_setprio(1);
#pragma unroll
                for (int jt = 0; jt < 4; ++jt) {
                    int jrow = (jt << 4) + qcol;
#pragma unroll
                    for (int kb = 0; kb < 2; ++kb) {
                        bf16x8 ah = *reinterpret_cast<const bf16x8*>(&kh[jrow][(kb << 5) + (g4 << 3)]);
                        bf16x8 al = *reinterpret_cast<const bf16x8*>(&kl[jrow][(kb << 5) + (g4 << 3)]);
                        sacc[jt] = __builtin_amdgcn_mfma_f32_16x16x32_bf16(ah, qfh[ti][kb], sacc[jt], 0, 0, 0);
                        sacc[jt] = __builtin_amdgcn_mfma_f32_16x16x32_bf16(al, qfh[ti][kb], sacc[jt], 0, 0, 0);
                        sacc[jt] = __builtin_amdgcn_mfma_f32_16x16x32_bf16(ah, qfl[ti][kb], sacc[jt], 0, 0, 0);
                    }
                }
                __builtin_amdgcn_s_setprio(0);

                float sv[16];
                float mx = -3.0e38f;
#pragma unroll
                for (int jt = 0; jt < 4; ++jt)
#pragma unroll
                    for (int r = 0; r < 4; ++r) {
                        float s = sacc[jt][r] * 0.125f;
                        if (c == T) {
                            int j_loc = (jt << 4) + (g4 << 2) + r;
                            if (j_loc > q_loc) s = -3.0e38f;
                        }
                        sv[(jt << 2) + r] = s;
                        mx = fmaxf(mx, s);
                    }
                mx = fmaxf(mx, __shfl_xor(mx, 16, 64));
                mx = fmaxf(mx, __shfl_xor(mx, 32, 64));
                if (!__all(mx <= m_r[ti] + 8.0f)) {
                    float mnew = fmaxf(m_r[ti], mx);
                    float ef = __expf(m_r[ti] - mnew);
                    l_r[ti] *= ef;
#pragma unroll
                    for (int dt = 0; dt < 4; ++dt) oacc[ti][dt] *= ef;
                    m_r[ti] = mnew;
                }
                float ps = 0.0f;
#pragma unroll
                for (int e = 0; e < 16; ++e) {
                    float p = __expf(sv[e] - m_r[ti]);
                    sv[e] = p;
                    ps += p;
                }
                ps += __shfl_xor(ps, 16, 64);
                ps += __shfl_xor(ps, 32, 64);
                l_r[ti] += ps;

                unsigned hwp[8], lwp[8];
#pragma unroll
                for (int jt = 0; jt < 4; ++jt) {
                    split_pair(sv[(jt << 2) + 0], sv[(jt << 2) + 1], hwp[(jt << 1) + 0], lwp[(jt << 1) + 0]);
                    split_pair(sv[(jt << 2) + 2], sv[(jt << 2) + 3], hwp[(jt << 1) + 1], lwp[(jt << 1) + 1]);
                }

                __builtin_amdgcn_s_setprio(1);
#pragma unroll
                for (int kb2 = 0; kb2 < 2; ++kb2) {
                    bf16x8 ph, pl;
#pragma unroll
                    for (int ip = 0; ip < 4; ++ip) {
                        int srcl = (((g4 & 1) << 1) + (ip >> 1)) * 16 + qcol;
                        unsigned hA = __shfl(hwp[(kb2 << 2) + (ip & 1)], srcl, 64);
                        unsigned hB = __shfl(hwp[(kb2 << 2) + 2 + (ip & 1)], srcl, 64);
                        unsigned lA = __shfl(lwp[(kb2 << 2) + (ip & 1)], srcl, 64);
                        unsigned lB = __shfl(lwp[(kb2 << 2) + 2 + (ip & 1)], srcl, 64);
                        reinterpret_cast<unsigned*>(&ph)[ip] = selhi ? hB : hA;
                        reinterpret_cast<unsigned*>(&pl)[ip] = selhi ? lB : lA;
                    }
#pragma unroll
                    for (int dt = 0; dt < 4; ++dt) {
                        int drow = (dt << 4) + qcol;
                        bf16x8 ah = *reinterpret_cast<const bf16x8*>(&vh[drow][(kb2 << 5) + (g4 << 3)]);
                        bf16x8 al = *reinterpret_cast<const bf16x8*>(&vl[drow][(kb2 << 5) + (g4 << 3)]);
                        oacc[ti][dt] = __builtin_amdgcn_mfma_f32_16x16x32_bf16(ah, ph, oacc[ti][dt], 0, 0, 0);
                        oacc[ti][dt] = __builtin_amdgcn_mfma_f32_16x16x32_bf16(al, ph, oacc[ti][dt], 0, 0, 0);
                        oacc[ti][dt] = __builtin_amdgcn_mfma_f32_16x16x32_bf16(ah, pl, oacc[ti][dt], 0, 0, 0);
                    }
                }
                __builtin_amdgcn_s_setprio(0);
            }
        }
        __syncthreads();   // all LDS reads done before next chunk's staging
    }

    // ---- epilogue (both tiles) ----
    float dsum = 0.0f;
#pragma unroll
    for (int ti = 0; ti < 2; ++ti) {
        int T = ti ? tLo : tHi;
        float invl = 1.0f / l_r[ti];
        float* orow = o_io + (size_t)(rowbase + (T << 6) + q_loc) * DIMS + col0;
#pragma unroll
        for (int dt = 0; dt < 4; ++dt) {
            float4 ov = make_float4(oacc[ti][dt][0] * invl, oacc[ti][dt][1] * invl,
                                    oacc[ti][dt][2] * invl, oacc[ti][dt][3] * invl);
            float* addr = orow + (dt << 4) + (g4 << 2);
            if (DIFF) {
                float4 pv4 = ld4(addr);
                dsum += fabsf(ov.x - pv4.x) + fabsf(ov.y - pv4.y)
                      + fabsf(ov.z - pv4.z) + fabsf(ov.w - pv4.w);
            }
            st4(addr, ov);
        }
    }
    if (DIFF) {
        float s = wave_sum64(dsum);
        if (lane == 0) dred[wv] = s;
        __syncthreads();
        if (tid == 0) {
            double tot = (double)(dred[0] + dred[1] + dred[2] + dred[3]);
            unsigned long long q = (unsigned long long)(tot * FIXSCALE + 0.5);
            atomicAdd(&diff_acc[w], q);
        }
    }
}

// -------- qacc[u,:] += scramble(o)[u,:]  (torch q_cur += iter_out) -----------
__global__ __launch_bounds__(256)
void scatter_add_kernel(float* __restrict__ qacc, const float* __restrict__ o) {
    size_t gid = (size_t)blockIdx.x * 256 + threadIdx.x;
    size_t flat = gid << 2;
    int uu = (int)(flat >> 6);
    int col = (int)(flat & 63);
    int r = uu >> 4, h = uu & 15;
    int s = r & 511;
    int rb = r - s;
    size_t src = ((size_t)(rb + h * 32 + (s >> 4)) << 10)
               + (size_t)((s & 15) << 6) + col;
    float4 a = ld4(qacc + flat);
    float4 bv = ld4(o + src);
    st4(qacc + flat, make_float4(a.x + bv.x, a.y + bv.y, a.z + bv.z, a.w + bv.w));
}

__global__ void init_ctrl_kernel(unsigned long long* __restrict__ dacc,
                                 int* __restrict__ conv) {
    int i = threadIdx.x;
    if (i < 8) { dacc[i] = 0ULL; conv[i] = 0; }
}

__global__ void conv_from_acc_kernel(const unsigned long long* __restrict__ dacc,
                                     int* __restrict__ conv) {
    int w = threadIdx.x;
    if (w < 8) {
        float mean = (float)((double)dacc[w] * (1.0 / (FIXSCALE * 2097152.0)));
        conv[w] = (mean < 0.01f + 0.1f * mean) ? 1 : 0;
    }
}

// -------- unscramble src into packed-hl preout [B,S,DIMS] --------------------
__global__ __launch_bounds__(256)
void unscramble_pack_kernel(const float* __restrict__ src, unsigned* __restrict__ outp) {
    size_t gid = (size_t)blockIdx.x * 256 + threadIdx.x;
    size_t flat = gid << 2;
    int r = (int)(flat >> 10);
    int e = (int)(flat & 1023);
    int h2 = e >> 6, d2 = e & 63;
    int s2 = r & 511;
    int rb = r - s2;
    size_t sidx = ((size_t)(rb + h2 * 32 + (s2 >> 4)) << 10) + (size_t)((s2 & 15) << 6) + d2;
    float4 v = ld4(src + sidx);
    uint4 pk;
    pk.x = pack_hl(v.x); pk.y = pack_hl(v.y); pk.z = pack_hl(v.z); pk.w = pack_hl(v.w);
    *reinterpret_cast<uint4*>(outp + flat) = pk;
}

extern "C" void kernel_launch(void* const* d_in, const int* in_sizes, int n_in,
                              void* d_out, int out_size, void* d_ws, size_t ws_size,
                              hipStream_t stream) {
    (void)in_sizes; (void)n_in; (void)out_size; (void)ws_size;
    const float* x   = (const float*)d_in[0];
    const float* Wq  = (const float*)d_in[1];
    const float* bq  = (const float*)d_in[2];
    const float* Wk  = (const float*)d_in[3];
    const float* Wv  = (const float*)d_in[4];
    const float* bv  = (const float*)d_in[5];
    const float* Wo  = (const float*)d_in[6];
    const float* bo  = (const float*)d_in[7];
    const float* lna = (const float*)d_in[8];
    const float* lnb = (const float*)d_in[9];
    const float* lqw = (const float*)d_in[10];
    const float* lqb = (const float*)d_in[11];
    const float* lkw = (const float*)d_in[12];
    const float* lkb = (const float*)d_in[13];
    const float* lvw = (const float*)d_in[14];
    const float* lvb = (const float*)d_in[15];

    // ws: [4 KiB ctrl][R1 qacc][R2 xnhl->khl->preout_hl][R3 v->o] = 192 MiB + 4 KiB
    const size_t BUF = (size_t)NROWS * DIMS;      // 16M elements
    unsigned long long* dacc = (unsigned long long*)d_ws;
    int* conv = (int*)(dacc + 8);
    float* R1 = (float*)((char*)d_ws + 4096);
    float* R2 = R1 + BUF;
    float* R3 = R2 + BUF;
    float* E  = (float*)d_out;     // k f32 -> vthl plane -> final out

    const float scale = 0.35355339059327373f;     // 64^-0.25

    // 1. xnhl = pack(LN(x)) -> R2
    ln1024_pack_kernel<<<NROWS, 256, 0, stream>>>(x, lna, (unsigned*)R2);

    // 2. q,k,v GEMMs; head-LN fused into q and k epilogues
    dim3 gg(NROWS / 128, DIMS / 128);
    gemm_hl_kernel<1><<<gg, 256, 0, stream>>>((const unsigned*)R2, Wq, bq, R1, scale, 1, lnb);
    gemm_hl_kernel<1><<<gg, 256, 0, stream>>>((const unsigned*)R2, Wk, bq, E,  scale, 0, lnb);
    gemm_hl_kernel<0><<<gg, 256, 0, stream>>>((const unsigned*)R2, Wv, bv, R3, 1.0f, 1, lnb);

    // 3. kp plane (xnhl dead): E -> R2 ; vt plane (k dead): R3 -> E
    proj64_khl_kernel<<<NUNITS / 64, 256, 0, stream>>>(E, lkw, lkb, lnb, (unsigned*)R2);
    proj64_vthl_kernel<<<NUNITS / 64, 256, 0, stream>>>(R3, lvw, lvb, (unsigned*)E);

    // 4. control init
    init_ctrl_kernel<<<1, 64, 0, stream>>>(dacc, conv);

    const unsigned* KHL = (const unsigned*)R2;
    const unsigned* VTHL = (const unsigned*)E;

    // 5. it 0: o0 -> R3 (v f32 dead); 2048 blocks = 4 tile-pairs x 512 units
    attn_mfma_kernel<0, 0><<<512 * 4, 256, 0, stream>>>(R1, KHL, VTHL, R3, lqw, lqb, lnb, dacc, conv);
    // 6. qacc += scr(o0)
    scatter_add_kernel<<<NROWS * DIMS / 4 / 256, 256, 0, stream>>>(R1, R3);
    // 7. it 1: o1 -> R3 in place, fused per-window diff vs o0
    attn_mfma_kernel<1, 0><<<512 * 4, 256, 0, stream>>>(R1, KHL, VTHL, R3, lqw, lqb, lnb, dacc, conv);
    // 8. conv flags
    conv_from_acc_kernel<<<1, 64, 0, stream>>>(dacc, conv);
    // 9. qacc += scr(o1)
    scatter_add_kernel<<<NROWS * DIMS / 4 / 256, 256, 0, stream>>>(R1, R3);
    // 10. it 2: o2 -> R3, skipped for converged windows (keeps o1)
    attn_mfma_kernel<0, 1><<<512 * 4, 256, 0, stream>>>(R1, KHL, VTHL, R3, lqw, lqb, lnb, dacc, conv);

    // 11. preout_hl = pack(unscramble(R3)) -> R2 (khl dead)
    unscramble_pack_kernel<<<NROWS * DIMS / 4 / 256, 256, 0, stream>>>(R3, (unsigned*)R2);
    // 12. out = preout @ Wo^T + bo -> d_out (vthl dead)
    gemm_hl_kernel<0><<<gg, 256, 0, stream>>>((const unsigned*)R2, Wo, bo, (float*)d_out, 1.0f, 1, lnb);
}

// Round 14
// 981.693 us; speedup vs baseline: 1.4846x; 1.0209x over previous
//
#include <hip/hip_runtime.h>
#include <math.h>

// Problem constants (from reference)
#define DIMS   1024
#define NHEAD  16
#define HD     64
#define WIN    512
#define CTX    4096
#define NBATCH 4
#define NROWS  (NBATCH*CTX)        // 16384 total sequence rows
#define NUNITS (NROWS*NHEAD)       // 262144 (row,head) units
#define LNEPS  1e-5f
#define FIXSCALE 16777216.0        // 2^24 fixed-point for deterministic diff

typedef __attribute__((ext_vector_type(8))) short bf16x8;   // 8 bf16 (4 VGPR)
typedef __attribute__((ext_vector_type(4))) float f32x4;    // MFMA C/D

__device__ __forceinline__ float4 ld4(const float* p) { return *reinterpret_cast<const float4*>(p); }
__device__ __forceinline__ void st4(float* p, float4 v) { *reinterpret_cast<float4*>(p) = v; }

__device__ __forceinline__ float wave_sum64(float v) {
#pragma unroll
    for (int off = 32; off; off >>= 1) v += __shfl_xor(v, off, 64);
    return v;
}
__device__ __forceinline__ float grp16_sum(float v) {
    v += __shfl_xor(v, 1, 64);
    v += __shfl_xor(v, 2, 64);
    v += __shfl_xor(v, 4, 64);
    v += __shfl_xor(v, 8, 64);
    return v;
}

// round-to-nearest-even bf16 of x, packed split: (hi<<16)|lo with hi+lo ~= x (err ~2^-17)
__device__ __forceinline__ unsigned bf16_rn_bits(float x) {
    unsigned u = __float_as_uint(x);
    return (u + 0x7fffu + ((u >> 16) & 1u)) >> 16;
}
__device__ __forceinline__ unsigned pack_hl(float x) {
    unsigned h = bf16_rn_bits(x);
    float hf = __uint_as_float(h << 16);
    unsigned l = bf16_rn_bits(x - hf);
    return (h << 16) | (l & 0xffffu);
}

// v_cvt_pk_bf16_f32: D[15:0]=bf16(a), D[31:16]=bf16(b)  (T12 recipe)
__device__ __forceinline__ unsigned cvtpk_bf16(float a, float b) {
    unsigned r;
    asm volatile("v_cvt_pk_bf16_f32 %0, %1, %2" : "=v"(r) : "v"(a), "v"(b));
    return r;
}
__device__ __forceinline__ void split_pair(float a, float b, unsigned& hw, unsigned& lw) {
    hw = cvtpk_bf16(a, b);
    float ha = __uint_as_float(hw << 16);
    float hb = __uint_as_float(hw & 0xffff0000u);
    lw = cvtpk_bf16(a - ha, b - hb);
}

// XOR-swizzled byte offset into a [rows][64] short LDS plane (stride 128 B)
__device__ __forceinline__ int swzo(int row, int kbyte) {
    return ((row << 7) + kbyte) ^ ((row & 7) << 4);
}

// -------- LayerNorm over D=1024 (row-wise), PACKED hi/lo output --------------
__global__ __launch_bounds__(256)
void ln1024_pack_kernel(const float* __restrict__ x, const float* __restrict__ w,
                        unsigned* __restrict__ outp) {
    int r = blockIdx.x;
    int tid = threadIdx.x;
    const float* xr = x + (size_t)r * DIMS;
    float4 v = ld4(xr + (tid << 2));
    __shared__ float red[8];
    float s = wave_sum64(v.x + v.y + v.z + v.w);
    int wv = tid >> 6, lane = tid & 63;
    if (lane == 0) red[wv] = s;
    __syncthreads();
    float mean = (red[0] + red[1] + red[2] + red[3]) * (1.0f / DIMS);
    float dx = v.x - mean, dy = v.y - mean, dz = v.z - mean, dw = v.w - mean;
    float ss = wave_sum64(dx*dx + dy*dy + dz*dz + dw*dw);
    if (lane == 0) red[4 + wv] = ss;
    __syncthreads();
    float inv = rsqrtf((red[4] + red[5] + red[6] + red[7]) * (1.0f / DIMS) + LNEPS);
    float4 wv4 = ld4(w + (tid << 2));
    uint4 pk;
    pk.x = pack_hl(dx * inv * wv4.x);
    pk.y = pack_hl(dy * inv * wv4.y);
    pk.z = pack_hl(dz * inv * wv4.z);
    pk.w = pack_hl(dw * inv * wv4.w);
    *reinterpret_cast<uint4*>(outp + (size_t)r * DIMS + (tid << 2)) = pk;
}

// -------- bf16 hi/lo 3-term MFMA GEMM ----------------------------------------
// DO_HLN: fused per-head LN epilogue. AMODE=0: A = packed-hl u32 stream.
// AMODE=1: A read from f32 buffer through the UNSCRAMBLE permutation + split
//          (replaces the standalone unscramble_pack pass; same bytes).
template<int DO_HLN, int AMODE>
__global__ __launch_bounds__(256, 2)
void gemm_hl_kernel(const unsigned* __restrict__ Ahl, const float* __restrict__ Af,
                    const float* __restrict__ W,
                    const float* __restrict__ bias, float* __restrict__ Cm,
                    float alpha, int has_bias, const float* __restrict__ lnw) {
    __shared__ short Ah[128 * 64], Al[128 * 64], Wh[128 * 64], Wl[128 * 64]; // 64 KiB
    int tid = threadIdx.x;
    int wid = tid >> 6, lane = tid & 63;
    int wm = (wid >> 1) << 6, wn = (wid & 1) << 6;
    int g4 = lane >> 4, l16 = lane & 15;
    int m0 = blockIdx.x << 7, n0 = blockIdx.y << 7;

    f32x4 acc[4][4] = {};

    int orow[4], okb[4];
#pragma unroll
    for (int j = 0; j < 4; ++j) {
        int oc = tid + (j << 8);
        orow[j] = oc >> 3;
        okb[j] = (oc & 7) << 4;
    }

    for (int k0 = 0; k0 < 1024; k0 += 64) {
        uint4 a0[4], a1[4];
        float4 af0[4], af1[4];
        float4 w0[4], w1[4];
#pragma unroll
        for (int j = 0; j < 4; ++j) {
            if (AMODE == 0) {
                const unsigned* ap = Ahl + (size_t)(m0 + orow[j]) * 1024 + k0 + (okb[j] >> 1);
                a0[j] = *reinterpret_cast<const uint4*>(ap);
                a1[j] = *reinterpret_cast<const uint4*>(ap + 4);
            } else {
                // unscramble permutation: out[r][e] = src[(rb + h2*32 + s2/16)][ (s2%16)*64 + d2 ]
                int r = m0 + orow[j];
                int e = k0 + (okb[j] >> 1);          // starting column 0..1023
                int s2 = r & 511;
                size_t src = ((size_t)((r - s2) + ((e >> 6) << 5) + (s2 >> 4)) << 10)
                           + (size_t)((s2 & 15) << 6) + (e & 63);
                af0[j] = ld4(Af + src);
                af1[j] = ld4(Af + src + 4);
            }
            const float* wp = W + (size_t)(n0 + orow[j]) * 1024 + k0 + (okb[j] >> 1);
            w0[j] = *reinterpret_cast<const float4*>(wp);
            w1[j] = *reinterpret_cast<const float4*>(wp + 4);
        }
        __syncthreads();   // prior iteration's fragment reads complete
#pragma unroll
        for (int j = 0; j < 4; ++j) {
            int off = swzo(orow[j], okb[j]);
            uint4 hi, lo;
            if (AMODE == 0) {
                hi.x = __byte_perm(a0[j].x, a0[j].y, 0x7632);
                hi.y = __byte_perm(a0[j].z, a0[j].w, 0x7632);
                hi.z = __byte_perm(a1[j].x, a1[j].y, 0x7632);
                hi.w = __byte_perm(a1[j].z, a1[j].w, 0x7632);
                lo.x = __byte_perm(a0[j].x, a0[j].y, 0x5410);
                lo.y = __byte_perm(a0[j].z, a0[j].w, 0x5410);
                lo.z = __byte_perm(a1[j].x, a1[j].y, 0x5410);
                lo.w = __byte_perm(a1[j].z, a1[j].w, 0x5410);
            } else {
                split_pair(af0[j].x, af0[j].y, hi.x, lo.x);
                split_pair(af0[j].z, af0[j].w, hi.y, lo.y);
                split_pair(af1[j].x, af1[j].y, hi.z, lo.z);
                split_pair(af1[j].z, af1[j].w, hi.w, lo.w);
            }
            *reinterpret_cast<uint4*>(reinterpret_cast<char*>(Ah) + off) = hi;
            *reinterpret_cast<uint4*>(reinterpret_cast<char*>(Al) + off) = lo;

            uint4 hw4, lw4;
            split_pair(w0[j].x, w0[j].y, hw4.x, lw4.x);
            split_pair(w0[j].z, w0[j].w, hw4.y, lw4.y);
            split_pair(w1[j].x, w1[j].y, hw4.z, lw4.z);
            split_pair(w1[j].z, w1[j].w, hw4.w, lw4.w);
            *reinterpret_cast<uint4*>(reinterpret_cast<char*>(Wh) + off) = hw4;
            *reinterpret_cast<uint4*>(reinterpret_cast<char*>(Wl) + off) = lw4;
        }
        __syncthreads();

#pragma unroll
        for (int kk = 0; kk < 2; ++kk) {
            bf16x8 afh[4], afl[4], wfh[4], wfl[4];
#pragma unroll
            for (int mt = 0; mt < 4; ++mt) {
                int row = wm + (mt << 4) + l16;
                int off = ((row << 7) + (kk << 6) + (g4 << 4)) ^ ((row & 7) << 4);
                afh[mt] = *reinterpret_cast<const bf16x8*>(reinterpret_cast<const char*>(Ah) + off);
                afl[mt] = *reinterpret_cast<const bf16x8*>(reinterpret_cast<const char*>(Al) + off);
            }
#pragma unroll
            for (int nt = 0; nt < 4; ++nt) {
                int row = wn + (nt << 4) + l16;
                int off = ((row << 7) + (kk << 6) + (g4 << 4)) ^ ((row & 7) << 4);
                wfh[nt] = *reinterpret_cast<const bf16x8*>(reinterpret_cast<const char*>(Wh) + off);
                wfl[nt] = *reinterpret_cast<const bf16x8*>(reinterpret_cast<const char*>(Wl) + off);
            }
#pragma unroll
            for (int mt = 0; mt < 4; ++mt)
#pragma unroll
                for (int nt = 0; nt < 4; ++nt) {
                    acc[mt][nt] = __builtin_amdgcn_mfma_f32_16x16x32_bf16(afh[mt], wfh[nt], acc[mt][nt], 0, 0, 0);
                    acc[mt][nt] = __builtin_amdgcn_mfma_f32_16x16x32_bf16(afl[mt], wfh[nt], acc[mt][nt], 0, 0, 0);
                    acc[mt][nt] = __builtin_amdgcn_mfma_f32_16x16x32_bf16(afh[mt], wfl[nt], acc[mt][nt], 0, 0, 0);
                }
        }
    }

    if (DO_HLN) {
        float bb[4];
#pragma unroll
        for (int nt = 0; nt < 4; ++nt)
            bb[nt] = has_bias ? bias[n0 + wn + (nt << 4) + l16] : 0.0f;
        float lw4[4];
#pragma unroll
        for (int nt = 0; nt < 4; ++nt) lw4[nt] = lnw[(nt << 4) + l16];
#pragma unroll
        for (int mt = 0; mt < 4; ++mt)
#pragma unroll
            for (int r = 0; r < 4; ++r) {
                float v[4];
                float s1 = 0.0f;
#pragma unroll
                for (int nt = 0; nt < 4; ++nt) {
                    v[nt] = alpha * (acc[mt][nt][r] + bb[nt]);
                    s1 += v[nt];
                }
                s1 = grp16_sum(s1);
                float mean = s1 * (1.0f / 64.0f);
                float s2 = 0.0f;
#pragma unroll
                for (int nt = 0; nt < 4; ++nt) { v[nt] -= mean; s2 += v[nt] * v[nt]; }
                s2 = grp16_sum(s2);
                float inv = rsqrtf(s2 * (1.0f / 64.0f) + LNEPS);
                int row = m0 + wm + (mt << 4) + (g4 << 2) + r;
#pragma unroll
                for (int nt = 0; nt < 4; ++nt)
                    Cm[(size_t)row * DIMS + n0 + wn + (nt << 4) + l16] = v[nt] * inv * lw4[nt];
            }
    } else {
#pragma unroll
        for (int mt = 0; mt < 4; ++mt)
#pragma unroll
            for (int nt = 0; nt < 4; ++nt) {
                int col = n0 + wn + (nt << 4) + l16;
                float bb = has_bias ? bias[col] : 0.0f;
#pragma unroll
                for (int r = 0; r < 4; ++r) {
                    int row = m0 + wm + (mt << 4) + (g4 << 2) + r;
                    Cm[(size_t)row * DIMS + col] = alpha * (acc[mt][nt][r] + bb);
                }
            }
    }
}

// -------- kp projection + LN + hi/lo split -> packed K plane -----------------
__global__ __launch_bounds__(256)
void proj64_khl_kernel(const float* __restrict__ inp, const float* __restrict__ W,
                       const float* __restrict__ Wb, const float* __restrict__ lnw,
                       unsigned* __restrict__ plane) {
    int u0 = blockIdx.x << 6;
    __shared__ float As[64][68];
    __shared__ float Bs[64][68];
    int tid = threadIdx.x;
    for (int e = tid; e < 4096; e += 256) Bs[e & 63][e >> 6] = W[e];
    for (int e = tid; e < 1024; e += 256) {
        int row = e >> 4;
        int col = (e & 15) << 2;
        float4 v = ld4(inp + ((size_t)(u0 + row) << 6) + col);
        As[col + 0][row] = v.x; As[col + 1][row] = v.y;
        As[col + 2][row] = v.z; As[col + 3][row] = v.w;
    }
    __syncthreads();
    int tm = tid >> 4, tn = tid & 15;
    float acc[4][4] = {};
#pragma unroll
    for (int k = 0; k < 64; ++k) {
        float4 av = ld4(&As[k][tm << 2]);
        float4 bv = ld4(&Bs[k][tn << 2]);
        float aa[4] = {av.x, av.y, av.z, av.w};
        float bb[4] = {bv.x, bv.y, bv.z, bv.w};
#pragma unroll
        for (int mm = 0; mm < 4; ++mm)
#pragma unroll
            for (int nn = 0; nn < 4; ++nn)
                acc[mm][nn] = fmaf(aa[mm], bb[nn], acc[mm][nn]);
    }
    float bb4[4] = {Wb[(tn << 2) + 0], Wb[(tn << 2) + 1], Wb[(tn << 2) + 2], Wb[(tn << 2) + 3]};
    float lw4[4] = {lnw[(tn << 2) + 0], lnw[(tn << 2) + 1], lnw[(tn << 2) + 2], lnw[(tn << 2) + 3]};
#pragma unroll
    for (int mm = 0; mm < 4; ++mm) {
        float o0 = acc[mm][0] + bb4[0], o1 = acc[mm][1] + bb4[1];
        float o2 = acc[mm][2] + bb4[2], o3 = acc[mm][3] + bb4[3];
        float mean = grp16_sum(o0 + o1 + o2 + o3) * (1.0f / 64.0f);
        float d0 = o0 - mean, d1 = o1 - mean, d2 = o2 - mean, d3 = o3 - mean;
        float var = grp16_sum(d0*d0 + d1*d1 + d2*d2 + d3*d3) * (1.0f / 64.0f);
        float inv = rsqrtf(var + LNEPS);
        o0 = d0 * inv * lw4[0]; o1 = d1 * inv * lw4[1];
        o2 = d2 * inv * lw4[2]; o3 = d3 * inv * lw4[3];
        int u_p = u0 + (tm << 2) + mm;
        int r = u_p >> 4, h = u_p & 15;
        int s = r & 511;
        int ua = ((r >> 9) << 4) + h;
        size_t punit = (size_t)ua * 512 + s;
        uint4 pk;
        pk.x = pack_hl(o0); pk.y = pack_hl(o1); pk.z = pack_hl(o2); pk.w = pack_hl(o3);
        *reinterpret_cast<uint4*>(plane + (punit << 6) + (tn << 2)) = pk;
    }
}

// -------- vp projection + hi/lo split -> packed transposed V plane -----------
__global__ __launch_bounds__(256)
void proj64_vthl_kernel(const float* __restrict__ inp, const float* __restrict__ W,
                        const float* __restrict__ Wb, unsigned* __restrict__ plane) {
    int u0 = blockIdx.x << 6;
    __shared__ float As[64][68];
    __shared__ float Bs[64][68];
    int tid = threadIdx.x;
    for (int e = tid; e < 4096; e += 256) Bs[e & 63][e >> 6] = W[e];
    for (int e = tid; e < 1024; e += 256) {
        int row = e >> 4;
        int col = (e & 15) << 2;
        float4 v = ld4(inp + ((size_t)(u0 + row) << 6) + col);
        As[col + 0][row] = v.x; As[col + 1][row] = v.y;
        As[col + 2][row] = v.z; As[col + 3][row] = v.w;
    }
    __syncthreads();
    int tm = tid >> 4, tn = tid & 15;
    float acc[4][4] = {};
#pragma unroll
    for (int k = 0; k < 64; ++k) {
        float4 av = ld4(&As[k][tm << 2]);
        float4 bv = ld4(&Bs[k][tn << 2]);
        float aa[4] = {av.x, av.y, av.z, av.w};
        float bb[4] = {bv.x, bv.y, bv.z, bv.w};
#pragma unroll
        for (int mm = 0; mm < 4; ++mm)
#pragma unroll
            for (int nn = 0; nn < 4; ++nn)
                acc[mm][nn] = fmaf(aa[mm], bb[nn], acc[mm][nn]);
    }
    float bb4[4] = {Wb[(tn << 2) + 0], Wb[(tn << 2) + 1], Wb[(tn << 2) + 2], Wb[(tn << 2) + 3]};
#pragma unroll
    for (int mm = 0; mm < 4; ++mm) {
        int u_p = u0 + (tm << 2) + mm;
        int r = u_p >> 4, h = u_p & 15;
        int s = r & 511;
        int ua = ((r >> 9) << 4) + h;
        size_t base = ((size_t)(ua * 8 + (s >> 6)) << 12) + (s & 63);
#pragma unroll
        for (int nn = 0; nn < 4; ++nn) {
            int d = (tn << 2) + nn;
            plane[base + ((size_t)d << 6)] = pack_hl(acc[mm][nn] + bb4[nn]);
        }
    }
}

// -------- fused MFMA attention: TWO q-tiles per block (R9-proven core) -------
// USE_CONV now computes the convergence gate inline from dacc (fixed-point,
// deterministic; dacc complete at kernel boundary after it-1).
template<int DIFF, int USE_CONV>
__global__ __launch_bounds__(256)
void attn_mfma_kernel(const float* __restrict__ qacc, const unsigned* __restrict__ khl,
                      const unsigned* __restrict__ vthl, float* __restrict__ o_io,
                      const float* __restrict__ lqw, const float* __restrict__ lqb,
                      const float* __restrict__ lnw,
                      unsigned long long* __restrict__ diff_acc) {
    __shared__ short kh[64][72], kl[64][72], vh[64][72], vl[64][72];   // 36864 B
    __shared__ float dred[4];

    int blk = blockIdx.x;
    int u = blk & 511;
    int pr = blk >> 9;             // 0..3
    int tHi = 7 - (pr << 1);       // 7,5,3,1 (heavy pairs launch first)
    int tLo = tHi - 1;             // 6,4,2,0
    int h = u & 15;
    int w = (u >> 4) & 7;
    int b = u >> 7;
    if (USE_CONV) {
        float mean = (float)((double)diff_acc[w] * (1.0 / (FIXSCALE * 2097152.0)));
        if (mean < 0.01f + 0.1f * mean) return;   // window converged: keep o1
    }
    int rowbase = b * CTX + w * WIN;
    int col0 = h * HD;
    int tid = threadIdx.x;
    int wv = tid >> 6;
    int lane = tid & 63;
    int g4 = lane >> 4;
    int qcol = lane & 15;
    int q_loc = (wv << 4) + qcol;
    int selhi = g4 >> 1;

    const unsigned* kbase = khl + (((size_t)u * 512) << 6);
    const unsigned* vbase = vthl + (((size_t)u * 8) << 12);

    // ---- prefetch chunk 0 K,V (hides under phase A) ----
    uint4 kpre[4], vpre[4];
#pragma unroll
    for (int rr = 0; rr < 4; ++rr) {
        int row = (wv << 4) + (rr << 2) + g4;
        kpre[rr] = *reinterpret_cast<const uint4*>(kbase + ((size_t)row << 6) + (qcol << 2));
        vpre[rr] = *reinterpret_cast<const uint4*>(vbase + ((size_t)row << 6) + (qcol << 2));
    }

    // ---- phase A: stage lqw once; per tile qp^T = mfma(lqw, qacc^T) + LN ----
#pragma unroll
    for (int rr = 0; rr < 4; ++rr) {
        int row = (wv << 4) + (rr << 2) + g4;
        float4 v = ld4(lqw + (row << 6) + (qcol << 2));
        unsigned h0, l0, h1, l1;
        split_pair(v.x, v.y, h0, l0);
        split_pair(v.z, v.w, h1, l1);
        *reinterpret_cast<uint2*>(&kh[row][qcol << 2]) = make_uint2(h0, h1);
        *reinterpret_cast<uint2*>(&kl[row][qcol << 2]) = make_uint2(l0, l1);
    }
    __syncthreads();   // lqw staged

    bf16x8 qfh[2][2], qfl[2][2];   // [tile][kb]
#pragma unroll
    for (int ti = 0; ti < 2; ++ti) {
        int T = ti ? tLo : tHi;
        bf16x8 bqh[2], bql[2];
        {
            const float* qrow = qacc + (size_t)(rowbase + (T << 6) + q_loc) * DIMS + col0;
#pragma unroll
            for (int kb = 0; kb < 2; ++kb) {
                float4 x0 = ld4(qrow + (kb << 5) + (g4 << 3));
                float4 x1 = ld4(qrow + (kb << 5) + (g4 << 3) + 4);
                unsigned hws[4], lws[4];
                split_pair(x0.x, x0.y, hws[0], lws[0]);
                split_pair(x0.z, x0.w, hws[1], lws[1]);
                split_pair(x1.x, x1.y, hws[2], lws[2]);
                split_pair(x1.z, x1.w, hws[3], lws[3]);
#pragma unroll
                for (int p2 = 0; p2 < 4; ++p2) {
                    reinterpret_cast<unsigned*>(&bqh[kb])[p2] = hws[p2];
                    reinterpret_cast<unsigned*>(&bql[kb])[p2] = lws[p2];
                }
            }
        }
        f32x4 qpa[4] = {{0,0,0,0},{0,0,0,0},{0,0,0,0},{0,0,0,0}};
        __builtin_amdgcn_s_setprio(1);
#pragma unroll
        for (int jt = 0; jt < 4; ++jt) {
            int arow = (jt << 4) + qcol;
#pragma unroll
            for (int kb = 0; kb < 2; ++kb) {
                bf16x8 ah = *reinterpret_cast<const bf16x8*>(&kh[arow][(kb << 5) + (g4 << 3)]);
                bf16x8 al = *reinterpret_cast<const bf16x8*>(&kl[arow][(kb << 5) + (g4 << 3)]);
                qpa[jt] = __builtin_amdgcn_mfma_f32_16x16x32_bf16(ah, bqh[kb], qpa[jt], 0, 0, 0);
                qpa[jt] = __builtin_amdgcn_mfma_f32_16x16x32_bf16(al, bqh[kb], qpa[jt], 0, 0, 0);
                qpa[jt] = __builtin_amdgcn_mfma_f32_16x16x32_bf16(ah, bql[kb], qpa[jt], 0, 0, 0);
            }
        }
        __builtin_amdgcn_s_setprio(0);

        float vals[16];
        float s1 = 0.0f;
#pragma unroll
        for (int jt = 0; jt < 4; ++jt) {
            float4 b4 = ld4(lqb + (jt << 4) + (g4 << 2));
            const float* b4p = reinterpret_cast<const float*>(&b4);
#pragma unroll
            for (int r = 0; r < 4; ++r) {
                float v = qpa[jt][r] + b4p[r];
                vals[(jt << 2) + r] = v;
                s1 += v;
            }
        }
        s1 += __shfl_xor(s1, 16, 64);
        s1 += __shfl_xor(s1, 32, 64);
        float mean = s1 * (1.0f / 64.0f);
        float s2 = 0.0f;
#pragma unroll
        for (int e = 0; e < 16; ++e) { float d = vals[e] - mean; vals[e] = d; s2 += d * d; }
        s2 += __shfl_xor(s2, 16, 64);
        s2 += __shfl_xor(s2, 32, 64);
        float inv = rsqrtf(s2 * (1.0f / 64.0f) + LNEPS);
#pragma unroll
        for (int jt = 0; jt < 4; ++jt) {
            float4 w4 = ld4(lnw + (jt << 4) + (g4 << 2));
            const float* w4p = reinterpret_cast<const float*>(&w4);
#pragma unroll
            for (int r = 0; r < 4; ++r) vals[(jt << 2) + r] *= inv * w4p[r];
        }

        unsigned hw[8], lw[8];
#pragma unroll
        for (int jt = 0; jt < 4; ++jt) {
            split_pair(vals[(jt << 2) + 0], vals[(jt << 2) + 1], hw[(jt << 1) + 0], lw[(jt << 1) + 0]);
            split_pair(vals[(jt << 2) + 2], vals[(jt << 2) + 3], hw[(jt << 1) + 1], lw[(jt << 1) + 1]);
        }
#pragma unroll
        for (int kb = 0; kb < 2; ++kb)
#pragma unroll
            for (int ip = 0; ip < 4; ++ip) {
                int srcl = (((g4 & 1) << 1) + (ip >> 1)) * 16 + qcol;
                unsigned hA = __shfl(hw[(kb << 2) + (ip & 1)], srcl, 64);
                unsigned hB = __shfl(hw[(kb << 2) + 2 + (ip & 1)], srcl, 64);
                unsigned lA = __shfl(lw[(kb << 2) + (ip & 1)], srcl, 64);
                unsigned lB = __shfl(lw[(kb << 2) + 2 + (ip & 1)], srcl, 64);
                reinterpret_cast<unsigned*>(&qfh[ti][kb])[ip] = selhi ? hB : hA;
                reinterpret_cast<unsigned*>(&qfl[ti][kb])[ip] = selhi ? lB : lA;
            }
    }
    __syncthreads();   // phase-A LDS reads done; planes free for K/V

    // ---- flash loop over chunks (both tiles share staged K/V) ----
    float m_r[2] = {-INFINITY, -INFINITY}, l_r[2] = {0.0f, 0.0f};
    f32x4 oacc[2][4] = {};

    for (int c = 0; c <= tHi; ++c) {
#pragma unroll
        for (int rr = 0; rr < 4; ++rr) {
            int row = (wv << 4) + (rr << 2) + g4;
            uint4 pk = kpre[rr];
            unsigned* khp = reinterpret_cast<unsigned*>(&kh[row][qcol << 2]);
            khp[0] = __byte_perm(pk.x, pk.y, 0x7632);
            khp[1] = __byte_perm(pk.z, pk.w, 0x7632);
            unsigned* klp = reinterpret_cast<unsigned*>(&kl[row][qcol << 2]);
            klp[0] = __byte_perm(pk.x, pk.y, 0x5410);
            klp[1] = __byte_perm(pk.z, pk.w, 0x5410);
            uint4 pv = vpre[rr];
            unsigned* vhp = reinterpret_cast<unsigned*>(&vh[row][qcol << 2]);
            vhp[0] = __byte_perm(pv.x, pv.y, 0x7632);
            vhp[1] = __byte_perm(pv.z, pv.w, 0x7632);
            unsigned* vlp = reinterpret_cast<unsigned*>(&vl[row][qcol << 2]);
            vlp[0] = __byte_perm(pv.x, pv.y, 0x5410);
            vlp[1] = __byte_perm(pv.z, pv.w, 0x5410);
        }
        if (c < tHi) {
            const unsigned* ksrc = kbase + (((size_t)(c + 1) * 64) << 6);
            const unsigned* vsrc = vbase + (((size_t)(c + 1)) << 12);
#pragma unroll
            for (int rr = 0; rr < 4; ++rr) {
                int row = (wv << 4) + (rr << 2) + g4;
                kpre[rr] = *reinterpret_cast<const uint4*>(ksrc + ((size_t)row << 6) + (qcol << 2));
                vpre[rr] = *reinterpret_cast<const uint4*>(vsrc + ((size_t)row << 6) + (qcol << 2));
            }
        }
        __syncthreads();

#pragma unroll
        for (int ti = 0; ti < 2; ++ti) {
            if (ti == 0 || c <= tLo) {      // wave-uniform predicate
                int T = ti ? tLo : tHi;

                f32x4 sacc[4] = {{0,0,0,0},{0,0,0,0},{0,0,0,0},{0,0,0,0}};
                __builtin_amdgcn_s_setprio(1);
#pragma unroll
                for (int jt = 0; jt < 4; ++jt) {
                    int jrow = (jt << 4) + qcol;
#pragma unroll
                    for (int kb = 0; kb < 2; ++kb) {
                        bf16x8 ah = *reinterpret_cast<const bf16x8*>(&kh[jrow][(kb << 5) + (g4 << 3)]);
                        bf16x8 al = *reinterpret_cast<const bf16x8*>(&kl[jrow][(kb << 5) + (g4 << 3)]);
                        sacc[jt] = __builtin_amdgcn_mfma_f32_16x16x32_bf16(ah, qfh[ti][kb], sacc[jt], 0, 0, 0);
                        sacc[jt] = __builtin_amdgcn_mfma_f32_16x16x32_bf16(al, qfh[ti][kb], sacc[jt], 0, 0, 0);
                        sacc[jt] = __builtin_amdgcn_mfma_f32_16x16x32_bf16(ah, qfl[ti][kb], sacc[jt], 0, 0, 0);
                    }
                }
                __builtin_amdgcn_s_setprio(0);

                float sv[16];
                float mx = -3.0e38f;
#pragma unroll
                for (int jt = 0; jt < 4; ++jt)
#pragma unroll
                    for (int r = 0; r < 4; ++r) {
                        float s = sacc[jt][r] * 0.125f;
                        if (c == T) {
                            int j_loc = (jt << 4) + (g4 << 2) + r;
                            if (j_loc > q_loc) s = -3.0e38f;
                        }
                        sv[(jt << 2) + r] = s;
                        mx = fmaxf(mx, s);
                    }
                mx = fmaxf(mx, __shfl_xor(mx, 16, 64));
                mx = fmaxf(mx, __shfl_xor(mx, 32, 64));
                if (!__all(mx <= m_r[ti] + 8.0f)) {
                    float mnew = fmaxf(m_r[ti], mx);
                    float ef = __expf(m_r[ti] - mnew);
                    l_r[ti] *= ef;
#pragma unroll
                    for (int dt = 0; dt < 4; ++dt) oacc[ti][dt] *= ef;
                    m_r[ti] = mnew;
                }
                float ps = 0.0f;
#pragma unroll
                for (int e = 0; e < 16; ++e) {
                    float p = __expf(sv[e] - m_r[ti]);
                    sv[e] = p;
                    ps += p;
                }
                ps += __shfl_xor(ps, 16, 64);
                ps += __shfl_xor(ps, 32, 64);
                l_r[ti] += ps;

                unsigned hwp[8], lwp[8];
#pragma unroll
                for (int jt = 0; jt < 4; ++jt) {
                    split_pair(sv[(jt << 2) + 0], sv[(jt << 2) + 1], hwp[(jt << 1) + 0], lwp[(jt << 1) + 0]);
                    split_pair(sv[(jt << 2) + 2], sv[(jt << 2) + 3], hwp[(jt << 1) + 1], lwp[(jt << 1) + 1]);
                }

                __builtin_amdgcn_s_setprio(1);
#pragma unroll
                for (int kb2 = 0; kb2 < 2; ++kb2) {
                    bf16x8 ph, pl;
#pragma unroll
                    for (int ip = 0; ip < 4; ++ip) {
                        int srcl = (((g4 & 1) << 1) + (ip >> 1)) * 16 + qcol;
                        unsigned hA = __shfl(hwp[(kb2 << 2) + (ip & 1)], srcl, 64);
                        unsigned hB = __shfl(hwp[(kb2 << 2) + 2 + (ip & 1)], srcl, 64);
                        unsigned lA = __shfl(lwp[(kb2 << 2) + (ip & 1)], srcl, 64);
                        unsigned lB = __shfl(lwp[(kb2 << 2) + 2 + (ip & 1)], srcl, 64);
                        reinterpret_cast<unsigned*>(&ph)[ip] = selhi ? hB : hA;
                        reinterpret_cast<unsigned*>(&pl)[ip] = selhi ? lB : lA;
                    }
#pragma unroll
                    for (int dt = 0; dt < 4; ++dt) {
                        int drow = (dt << 4) + qcol;
                        bf16x8 ah = *reinterpret_cast<const bf16x8*>(&vh[drow][(kb2 << 5) + (g4 << 3)]);
                        bf16x8 al = *reinterpret_cast<const bf16x8*>(&vl[drow][(kb2 << 5) + (g4 << 3)]);
                        oacc[ti][dt] = __builtin_amdgcn_mfma_f32_16x16x32_bf16(ah, ph, oacc[ti][dt], 0, 0, 0);
                        oacc[ti][dt] = __builtin_amdgcn_mfma_f32_16x16x32_bf16(al, ph, oacc[ti][dt], 0, 0, 0);
                        oacc[ti][dt] = __builtin_amdgcn_mfma_f32_16x16x32_bf16(ah, pl, oacc[ti][dt], 0, 0, 0);
                    }
                }
                __builtin_amdgcn_s_setprio(0);
            }
        }
        __syncthreads();   // all LDS reads done before next chunk's staging
    }

    // ---- epilogue (both tiles) ----
    float dsum = 0.0f;
#pragma unroll
    for (int ti = 0; ti < 2; ++ti) {
        int T = ti ? tLo : tHi;
        float invl = 1.0f / l_r[ti];
        float* orow = o_io + (size_t)(rowbase + (T << 6) + q_loc) * DIMS + col0;
#pragma unroll
        for (int dt = 0; dt < 4; ++dt) {
            float4 ov = make_float4(oacc[ti][dt][0] * invl, oacc[ti][dt][1] * invl,
                                    oacc[ti][dt][2] * invl, oacc[ti][dt][3] * invl);
            float* addr = orow + (dt << 4) + (g4 << 2);
            if (DIFF) {
                float4 pv4 = ld4(addr);
                dsum += fabsf(ov.x - pv4.x) + fabsf(ov.y - pv4.y)
                      + fabsf(ov.z - pv4.z) + fabsf(ov.w - pv4.w);
            }
            st4(addr, ov);
        }
    }
    if (DIFF) {
        float s = wave_sum64(dsum);
        if (lane == 0) dred[wv] = s;
        __syncthreads();
        if (tid == 0) {
            double tot = (double)(dred[0] + dred[1] + dred[2] + dred[3]);
            unsigned long long q = (unsigned long long)(tot * FIXSCALE + 0.5);
            atomicAdd(&diff_acc[w], q);
        }
    }
}

// -------- qacc[u,:] += scramble(o)[u,:]  (torch q_cur += iter_out) -----------
__global__ __launch_bounds__(256)
void scatter_add_kernel(float* __restrict__ qacc, const float* __restrict__ o) {
    size_t gid = (size_t)blockIdx.x * 256 + threadIdx.x;
    size_t flat = gid << 2;
    int uu = (int)(flat >> 6);
    int col = (int)(flat & 63);
    int r = uu >> 4, h = uu & 15;
    int s = r & 511;
    int rb = r - s;
    size_t src = ((size_t)(rb + h * 32 + (s >> 4)) << 10)
               + (size_t)((s & 15) << 6) + col;
    float4 a = ld4(qacc + flat);
    float4 bv = ld4(o + src);
    st4(qacc + flat, make_float4(a.x + bv.x, a.y + bv.y, a.z + bv.z, a.w + bv.w));
}

__global__ void init_ctrl_kernel(unsigned long long* __restrict__ dacc) {
    int i = threadIdx.x;
    if (i < 8) dacc[i] = 0ULL;
}

extern "C" void kernel_launch(void* const* d_in, const int* in_sizes, int n_in,
                              void* d_out, int out_size, void* d_ws, size_t ws_size,
                              hipStream_t stream) {
    (void)in_sizes; (void)n_in; (void)out_size; (void)ws_size;
    const float* x   = (const float*)d_in[0];
    const float* Wq  = (const float*)d_in[1];
    const float* bq  = (const float*)d_in[2];
    const float* Wk  = (const float*)d_in[3];
    const float* Wv  = (const float*)d_in[4];
    const float* bv  = (const float*)d_in[5];
    const float* Wo  = (const float*)d_in[6];
    const float* bo  = (const float*)d_in[7];
    const float* lna = (const float*)d_in[8];
    const float* lnb = (const float*)d_in[9];
    const float* lqw = (const float*)d_in[10];
    const float* lqb = (const float*)d_in[11];
    const float* lkw = (const float*)d_in[12];
    const float* lkb = (const float*)d_in[13];
    const float* lvw = (const float*)d_in[14];
    const float* lvb = (const float*)d_in[15];

    // ws: [4 KiB ctrl][R1 qacc][R2 xnhl->khl][R3 v->o] = 192 MiB + 4 KiB
    const size_t BUF = (size_t)NROWS * DIMS;      // 16M elements
    unsigned long long* dacc = (unsigned long long*)d_ws;
    float* R1 = (float*)((char*)d_ws + 4096);
    float* R2 = R1 + BUF;
    float* R3 = R2 + BUF;
    float* E  = (float*)d_out;     // k f32 -> vthl plane -> final out

    const float scale = 0.35355339059327373f;     // 64^-0.25

    // 1. xnhl = pack(LN(x)) -> R2
    ln1024_pack_kernel<<<NROWS, 256, 0, stream>>>(x, lna, (unsigned*)R2);

    // 2. q,k,v GEMMs; head-LN fused into q and k epilogues
    dim3 gg(NROWS / 128, DIMS / 128);
    gemm_hl_kernel<1, 0><<<gg, 256, 0, stream>>>((const unsigned*)R2, nullptr, Wq, bq, R1, scale, 1, lnb);
    gemm_hl_kernel<1, 0><<<gg, 256, 0, stream>>>((const unsigned*)R2, nullptr, Wk, bq, E,  scale, 0, lnb);
    gemm_hl_kernel<0, 0><<<gg, 256, 0, stream>>>((const unsigned*)R2, nullptr, Wv, bv, R3, 1.0f, 1, lnb);

    // 3. kp plane (xnhl dead): E -> R2 ; vt plane (k dead): R3 -> E
    proj64_khl_kernel<<<NUNITS / 64, 256, 0, stream>>>(E, lkw, lkb, lnb, (unsigned*)R2);
    proj64_vthl_kernel<<<NUNITS / 64, 256, 0, stream>>>(R3, lvw, lvb, (unsigned*)E);

    // 4. control init (zero diff accumulators)
    init_ctrl_kernel<<<1, 64, 0, stream>>>(dacc);

    const unsigned* KHL = (const unsigned*)R2;
    const unsigned* VTHL = (const unsigned*)E;

    // 5. it 0: o0 -> R3 (v f32 dead); 2048 blocks = 4 tile-pairs x 512 units
    attn_mfma_kernel<0, 0><<<512 * 4, 256, 0, stream>>>(R1, KHL, VTHL, R3, lqw, lqb, lnb, dacc);
    // 6. qacc += scr(o0)
    scatter_add_kernel<<<NROWS * DIMS / 4 / 256, 256, 0, stream>>>(R1, R3);
    // 7. it 1: o1 -> R3 in place, fused per-window diff vs o0
    attn_mfma_kernel<1, 0><<<512 * 4, 256, 0, stream>>>(R1, KHL, VTHL, R3, lqw, lqb, lnb, dacc);
    // 8. qacc += scr(o1)
    scatter_add_kernel<<<NROWS * DIMS / 4 / 256, 256, 0, stream>>>(R1, R3);
    // 9. it 2: o2 -> R3; convergence gate computed inline from dacc (keeps o1)
    attn_mfma_kernel<0, 1><<<512 * 4, 256, 0, stream>>>(R1, KHL, VTHL, R3, lqw, lqb, lnb, dacc);

    // 10. out = unscramble(R3) @ Wo^T + bo -> d_out (unscramble fused into A-staging)
    gemm_hl_kernel<0, 1><<<gg, 256, 0, stream>>>(nullptr, R3, Wo, bo, (float*)d_out, 1.0f, 1, lnb);
}